// Round 6
// baseline (357.715 us; speedup 1.0000x reference)
//
#include <hip/hip_runtime.h>
#include <math.h>

typedef unsigned long long u64;
typedef unsigned int u32;

#define BF 8
#define NPTS 16384
#define M_SN 1024
#define CCH 64
#define KNN 16
#define NTHR1 1024
#define KPER 16            // NPTS / NTHR1
#define TBL 4096
#define CCAP 2048
#define REM 1008           // M - 16 gripper slots

// output layout (flat float32, concatenated in return order)
constexpr size_t O0 = 0;                 // neighbor_feats 8*1024*16*64
constexpr size_t O1 = 8388608;           // supernode_xyz 8*1024*3
constexpr size_t O2 = 8413184;           // neighbor_mask 8*1024*16
constexpr size_t O3 = 8544256;           // out_idx 8*1024
constexpr size_t O4 = 8552448;           // out_valid 8*1024
constexpr size_t O5 = 8560640;           // out_bucket 8*1024

// workspace layout: [0]=flag, PW_OFF: packed float4 points, then split wn lists
#define PW_OFF ((size_t)256)
#define PW_BYTES ((size_t)BF * NPTS * 16)            // 2 MiB
#define SEG1_BYTES ((size_t)BF * M_SN * KNN * 8)     // 1 MiB per segment list

__device__ __forceinline__ bool is_valid_el(const void* vp, int mode, long long i) {
  if (mode == 1) return ((const unsigned char*)vp)[i] != 0;
  if (mode == 2) return ((const float*)vp)[i] != 0.0f;
  return ((const int*)vp)[i] != 0;
}

// monotone-decreasing encode: larger float -> smaller u32 (NaN sorts first; -inf last)
__device__ __forceinline__ u32 desc_enc(float f) {
  u32 u = __float_as_uint(f);
  u32 s = (u & 0x80000000u) ? ~u : (u | 0x80000000u);
  return ~s;
}
__device__ __forceinline__ float desc_dec(u32 e) {   // exact inverse of desc_enc
  u32 s = ~e;
  u32 u = (s & 0x80000000u) ? (s & 0x7FFFFFFFu) : ~s;
  return __uint_as_float(u);
}
__device__ __forceinline__ bool enc_finite(u32 d) {
  u32 s = ~d;
  u32 u = (s & 0x80000000u) ? (s & 0x7FFFFFFFu) : ~s;
  return (u & 0x7F800000u) != 0x7F800000u;
}

__device__ __forceinline__ u64 wave_min_u64(u64 v) {
#pragma unroll
  for (int d = 32; d >= 1; d >>= 1) {
    u32 lo = __shfl_xor((u32)(v & 0xFFFFFFFFu), d, 64);
    u32 hi = __shfl_xor((u32)(v >> 32), d, 64);
    u64 o = ((u64)hi << 32) | lo;
    if (o < v) v = o;
  }
  return v;
}

__device__ __forceinline__ u64 block_min_u64(u64 v, u64* red16, int t) {
  v = wave_min_u64(v);
  if ((t & 63) == 0) red16[t >> 6] = v;
  __syncthreads();
  if (t < 64) {
    u64 x = red16[t & 15];
    x = wave_min_u64(x);
    if (t == 0) red16[0] = x;
  }
  __syncthreads();
  u64 r = red16[0];
  __syncthreads();
  return r;
}

__device__ __forceinline__ int block_excl_scan(int val, int* scanb, int t, int* tot) {
  int incl = val;
#pragma unroll
  for (int d = 1; d < 64; d <<= 1) {
    int v = __shfl_up(incl, d, 64);
    if ((t & 63) >= d) incl += v;
  }
  if ((t & 63) == 63) scanb[t >> 6] = incl;
  __syncthreads();
  if (t < 64) {
    int ws = (t < 16) ? scanb[t] : 0;
#pragma unroll
    for (int d = 1; d < 16; d <<= 1) {
      int v = __shfl_up(ws, d, 64);
      if ((t & 63) >= d) ws += v;
    }
    if (t < 16) scanb[16 + t] = ws;
  }
  __syncthreads();
  int wv = t >> 6;
  int base = (wv == 0) ? 0 : scanb[16 + wv - 1];
  *tot = scanb[16 + 15];
  int r = base + incl - val;
  __syncthreads();
  return r;
}

__device__ __forceinline__ u64 shfl64_grp(u64 v, int src) {   // width-32 partitioned
  u32 lo = (u32)__shfl((int)(u32)(v & 0xFFFFFFFFu), src, 32);
  u32 hi = (u32)__shfl((int)(u32)(v >> 32), src, 32);
  return ((u64)hi << 32) | lo;
}

// ---------------------------------------------------------------------------
// topk_select: exact ordered top-T of (ek asc, idx asc) among cmask candidates.
// ---------------------------------------------------------------------------
template<bool ASC, bool SHIFTBIN>
__device__ __forceinline__ void topk_select(const u32* ek, const u32* bk, u32 cmask,
    int Twant, int* table, u64* cand, int* scanb, int* sh, int* outArr, int t) {
  for (int j = t; j < TBL; j += NTHR1) table[j] = 0;
  if (t == 6) sh[6] = 0x7FFFFFFF;
  if (t == 7) sh[7] = 1;
  __syncthreads();
#pragma unroll
  for (int k = 0; k < KPER; k++) {
    if ((cmask >> k) & 1u) {
      int bin = SHIFTBIN ? (int)(ek[k] >> 20) : (int)bk[k];
      atomicAdd(&table[bin], 1);
    }
  }
  __syncthreads();
  int c_[4]; int c4 = 0;
#pragma unroll
  for (int q = 0; q < 4; q++) { c_[q] = table[4 * t + q]; c4 += c_[q]; }
  int htot;
  int cum = block_excl_scan(c4, scanb, t, &htot);
  const int T = min(Twant, htot);
  int e_ = cum;
#pragma unroll
  for (int q = 0; q < 4; q++) {
    int nx = e_ + c_[q];
    if (T > 0 && e_ < T && nx >= T) atomicMin(&sh[6], 4 * t + q);
    table[4 * t + q] = e_;           // overwrite counts with exclusive cums
    e_ = nx;
  }
  __syncthreads();
  if (T <= 0) return;                // uniform; outArr stays -1; sh[7] stays 1
  const int B = sh[6];
#pragma unroll
  for (int k = 0; k < KPER; k++) {
    if ((cmask >> k) & 1u) {
      int bin = SHIFTBIN ? (int)(ek[k] >> 20) : (int)bk[k];
      if (bin <= B) {
        int pos = atomicAdd(&table[bin], 1);   // grouped placement per bin
        if (pos < CCAP)
          cand[pos] = ((u64)ek[k] << 32) | ((u64)(u32)bin << 14) | (u32)(k * NTHR1 + t);
      }
    }
  }
  __syncthreads();
  const int nc = table[B];           // inclusive end of bin B == total collected
  if (nc <= CCAP) {
    for (int c = t; c < nc; c += NTHR1) {
      u64 key = cand[c];
      int bin = (int)((key >> 14) & 0xFFFu);
      int s = bin ? table[bin - 1] : 0;        // segment start (end of bin-1)
      int e2 = table[bin];                     // segment end
      int r = s;
      for (int j = s; j < e2; j++) r += (cand[j] < key);
      if (r < T) {
        u32 enc = (u32)(key >> 32);
        int ix = (int)(key & 0x3FFFu);
        bool fin = ASC ? (enc < 0x7F800000u) : enc_finite(enc);
        outArr[r] = fin ? ix : (ix | (int)0x80000000);
      }
    }
  } else {
    if (t == 0) sh[7] = 0;
  }
  __syncthreads();
}

// ---------------- K0: detect how `valid` (bool) is stored (knn !pw fallback only) ----
__global__ void detect_valid(const unsigned* __restrict__ w, int nwords, int* __restrict__ flag) {
  __shared__ int cls;
  int t = threadIdx.x;
  if (t == 0) cls = 0;
  __syncthreads();
  int local = 0;
  for (int i = t; i < nwords; i += blockDim.x) {
    unsigned v = w[i];
    if (v == 0x3F800000u) local = 2;            // float32 storage
    else if (v != 0u && v != 1u) local = max(local, 1); // packed bytes
  }
  if (local) atomicMax(&cls, local);
  __syncthreads();
  if (t == 0) flag[0] = cls;                    // 0=int32, 1=uint8, 2=float32
}

// ---------------- K1: supernode sampling (one block per batch row) ----------------
// vmode is self-detected per block with the SAME full-buffer scan as detect_valid
// (do NOT infer element size from in_sizes -- that broke out_idx in round 2).
__global__ __launch_bounds__(1024)
void sample_kernel(const float* __restrict__ xyz, const void* __restrict__ validp,
                   const float* __restrict__ state, const int* __restrict__ mask_id,
                   const float* __restrict__ extra, const float* __restrict__ glob,
                   int vwords, float4* __restrict__ pw, float* __restrict__ out) {
  __shared__ u64 red16[16];
  __shared__ int table[TBL];        // 16 KB
  __shared__ int scanb[32];
  __shared__ int mpick[REM];
  __shared__ u64 cand[CCAP];        // 16 KB
  __shared__ int gsorted[REM];
  __shared__ int head_i[16];
  __shared__ int head_bk[16];
  __shared__ int sh[8];             // 0:rhv 1:first_valid 2:has_radius 3:vmode 6:B 7:ok

  const int b = blockIdx.x, t = threadIdx.x;
  const float* xyzb = xyz + (size_t)b * NPTS * 3;
  const int* midb = mask_id + (size_t)b * NPTS;
  const float* exb = extra + (size_t)b * NPTS;
  const float* glb = glob + (size_t)b * NPTS;

  if (t < 8) sh[t] = 0;
  if (t == 1) sh[1] = 0x7FFFFFFF;
  if (t < 16) gsorted[t] = -1;      // gripper winners default
  __syncthreads();

  // ---- storage-mode detection (identical classification to detect_valid) ----
  {
    const unsigned* w = (const unsigned*)validp;
    int local = 0;
    for (int i = t; i < vwords; i += NTHR1) {
      unsigned vv = w[i];
      if (vv == 0x3F800000u) local = 2;
      else if (vv != 0u && vv != 1u) local = max(local, 1);
    }
    if (local) atomicMax(&sh[3], local);
  }
  __syncthreads();
  const int vmode = sh[3];

  // ---- validity bits (element i = k*1024 + t) ----
  u32 vbits = 0;
#pragma unroll
  for (int k = 0; k < KPER; k++) {
    int i = k * NTHR1 + t;
    if (is_valid_el(validp, vmode, (long long)b * NPTS + i)) vbits |= 1u << k;
  }
  if (vbits) {
    atomicOr(&sh[0], 1);
    atomicMin(&sh[1], (__ffs(vbits) - 1) * NTHR1 + t);
  }

  // ---- gripper distances + packed point array for knn ----
  float gx = state[b * 8 + 0], gy = state[b * 8 + 1], gz = state[b * 8 + 2];
  float gd[KPER];
  u32 inr = 0;
#pragma unroll
  for (int k = 0; k < KPER; k++) {
    int i = k * NTHR1 + t;
    float px = xyzb[3 * i], py = xyzb[3 * i + 1], pz = xyzb[3 * i + 2];
    float dx = px - gx, dy = py - gy, dz = pz - gz;
    float d = sqrtf((dx * dx + dy * dy) + dz * dz);
    gd[k] = d;
    bool vb = (vbits >> k) & 1u;
    if (vb && d <= 0.1f) inr |= 1u << k;
    if (pw) {
      float sb = __fadd_rn(__fadd_rn(__fmul_rn(px, px), __fmul_rn(py, py)), __fmul_rn(pz, pz));
      pw[(size_t)b * NPTS + i] = make_float4(px, py, pz, vb ? sb : INFINITY);
    }
  }
  if (inr) atomicOr(&sh[2], 1);
  __syncthreads();

  const int rhv = sh[0];
  const int first_valid = rhv ? sh[1] : 0;
  const u32 elig = vbits & (sh[2] ? inr : 0xFFFFu);
  u32 sel = 0;

  // ---- gripper: exact ordered top-16 of (gdist asc, idx asc) over eligible ----
  {
    u32 ek[KPER];
#pragma unroll
    for (int k = 0; k < KPER; k++) ek[k] = __float_as_uint(gd[k]);  // gd>=0: bits asc
    topk_select<true, true>(ek, nullptr, elig, 16, table, cand, scanb, sh, gsorted, t);
    if (sh[7]) {
      if (t < 16) {
        int g = gsorted[t];
        head_i[t] = (g >= 0) ? g : first_valid;
        head_bk[t] = (g >= 0) ? 1 : -1;
      }
      __syncthreads();
      for (int j = 0; j < 16; j++) {
        if (head_bk[j] == 1) {
          int ix = head_i[j];
          if ((ix & (NTHR1 - 1)) == t) sel |= 1u << (ix >> 10);
        }
      }
    } else {
      // pathological-ties fallback: iterative extraction
      for (int it = 0; it < 16; ++it) {
        u64 best = ~0ull;
#pragma unroll
        for (int k = 0; k < KPER; k++) {
          if (((elig >> k) & 1u) && !((sel >> k) & 1u)) {
            u64 key = ((u64)__float_as_uint(gd[k]) << 32) | (u32)(k * NTHR1 + t);
            if (key < best) best = key;
          }
        }
        u64 w = block_min_u64(best, red16, t);
        bool keep = (w >> 32) < 0x7F800000ull;
        int idx = (int)(w & 0xFFFFFFFFu);
        if (t == 0) { head_i[it] = keep ? idx : first_valid; head_bk[it] = keep ? 1 : -1; }
        if (keep && (idx & (NTHR1 - 1)) == t) sel |= 1u << (idx >> 10);
      }
      __syncthreads();
    }
  }

  // ---- mask stage: min index per distinct mask_id among candidates ----
  for (int j = t; j < TBL; j += NTHR1) table[j] = 0x7FFFFFFF;
  __syncthreads();
#pragma unroll
  for (int k = 0; k < KPER; k++) {
    if (((vbits >> k) & 1u) && !((sel >> k) & 1u)) {
      int i = k * NTHR1 + t;
      int id = midb[i];
      if ((u32)id < TBL) atomicMin(&table[id], i);
    }
  }
  __syncthreads();
  int cnt = 0;
#pragma unroll
  for (int q = 0; q < 4; q++) cnt += (table[4 * t + q] != 0x7FFFFFFF);
  int mtot;
  int excl = block_excl_scan(cnt, scanb, t, &mtot);
  {
    int pos = excl;
#pragma unroll
    for (int q = 0; q < 4; q++) {
      int v = table[4 * t + q];
      if (v != 0x7FFFFFFF) { if (pos < REM) mpick[pos] = v; pos++; }
    }
  }
  __syncthreads();
  const int nm = min(mtot, REM);
  for (int j = 0; j < nm; j++) {
    int p = mpick[j];
    if ((p & (NTHR1 - 1)) == t) sel |= 1u << (p >> 10);
  }

  // ---- extra stage (only active when < 8 distinct mask ids) ----
  u32 extra_used = 0;
  if (nm < 8 && rhv) {
    u32 extrbits = 0;
    for (int j = 0; j < 8; j++) {
      u64 best = ~0ull;
#pragma unroll
      for (int k = 0; k < KPER; k++) {
        if (((vbits >> k) & 1u) && !((sel >> k) & 1u) && !((extrbits >> k) & 1u)) {
          int i = k * NTHR1 + t;
          u64 key = ((u64)desc_enc(exb[i]) << 32) | (u32)i;
          if (key < best) best = key;
        }
      }
      u64 w = block_min_u64(best, red16, t);
      if (w == ~0ull) break;
      int idx = (int)(w & 0xFFFFFFFFu);
      bool fin = enc_finite((u32)(w >> 32));
      if ((idx & (NTHR1 - 1)) == t) extrbits |= 1u << (idx >> 10);
      if (j >= nm && fin) {
        extra_used |= 1u << j;
        if (t == 0) mpick[j] = idx;
        if ((idx & (NTHR1 - 1)) == t) sel |= 1u << (idx >> 10);
      }
    }
    __syncthreads();
  }

  // ---- global stage: exact ordered top-1008 of (global_score desc, idx asc) ----
  {
    u32 cbits = vbits & ~sel;
    u32 ek[KPER], bk[KPER];
#pragma unroll
    for (int k = 0; k < KPER; k++) {
      if ((cbits >> k) & 1u) {
        float f = glb[k * NTHR1 + t];
        ek[k] = desc_enc(f);
        float g = fminf(fmaxf(f, 0.0f), 0.99999994f);
        bk[k] = 4095u - (u32)(g * 4096.0f);
      } else { ek[k] = 0xFFFFFFFFu; bk[k] = 4095u; }
    }
    for (int j = t; j < REM; j += NTHR1) gsorted[j] = -1;
    topk_select<false, false>(ek, bk, cbits, REM, table, cand, scanb, sh, gsorted, t);
    if (!sh[7]) {
      u32 gext = 0;
      for (int j = 0; j < REM; j++) {
        u64 best = ~0ull;
#pragma unroll
        for (int k = 0; k < KPER; k++) {
          if (((cbits >> k) & 1u) && !((gext >> k) & 1u)) {
            u64 key = ((u64)ek[k] << 32) | (u32)(k * NTHR1 + t);
            if (key < best) best = key;
          }
        }
        u64 w = block_min_u64(best, red16, t);
        if (w == ~0ull) break;
        int idx = (int)(w & 0xFFFFFFFFu);
        if ((idx & (NTHR1 - 1)) == t) gext |= 1u << (idx >> 10);
        if (t == 0) gsorted[j] = enc_finite((u32)(w >> 32)) ? idx : (idx | (int)0x80000000);
      }
      __syncthreads();
    }
  }

  // ---- emit out_idx / out_valid / out_bucket / supernode_xyz ----
  {
    int slot = t;
    int idx, bucket;
    if (slot < 16) {
      idx = head_i[slot];
      bucket = head_bk[slot];
    } else {
      int jj = slot - 16;
      bool mk = (jj < nm) || (jj < 8 && ((extra_used >> jj) & 1u));
      if (mk) { idx = mpick[jj]; bucket = 2; }
      else {
        int g = gsorted[jj];
        if (rhv && g >= 0) { idx = g; bucket = 0; }
        else { idx = first_valid; bucket = -1; }
      }
    }
    bool ov = rhv && is_valid_el(validp, vmode, (long long)b * NPTS + idx);
    int ob = ov ? bucket : -1;
    size_t o = (size_t)b * M_SN + slot;
    out[O3 + o] = (float)idx;
    out[O4 + o] = ov ? 1.0f : 0.0f;
    out[O5 + o] = (float)ob;
    out[O1 + 3 * o + 0] = xyzb[3 * idx + 0];
    out[O1 + 3 * o + 1] = xyzb[3 * idx + 1];
    out[O1 + 3 * o + 2] = xyzb[3 * idx + 2];
  }
}

// ---------------- K2: KNN-16 distance scan ----------------
// LDS-staged chunks + SPG=2 + lazy candidate buffer (NO per-accept sorted
// insertion -- R1/R5's serialized 12-op shuffle chain per accept was the
// dominant cost). Accepts append in parallel (ballot + prefix popcount) to a
// per-sn 64-slot LDS buffer; on (uniform) overflow, a 64-pass odd-even
// transposition sort across the 32 lanes compacts to the exact top-16 and
// tightens the threshold (decoded 16th-best). virgin accept-all phase until
// the first compaction makes the <16-finite edge exact (idx-asc ties).
// Keys (desc_enc(q)<<32)|idx are unique u64s -> exact total order everywhere.
#define NTHR2 256
#define CH 1024
#define SPG 2
#define SNBLK 16           // supernodes per knn block (8 groups * SPG)
#define BCAP 64

// ascending sort of first n (<=64) items of gb across the 32-lane group;
// lane sub returns items 2*sub (a0) and 2*sub+1 (a1); pads with ~0ull.
__device__ __forceinline__ void sort64g(const u64* gb, int n, int sub, u64& a0, u64& a1) {
  a0 = (2 * sub < n) ? gb[2 * sub] : ~0ull;
  a1 = (2 * sub + 1 < n) ? gb[2 * sub + 1] : ~0ull;
#pragma unroll
  for (int p = 0; p < 32; p++) {
    // even pass: within-lane (items 2i, 2i+1)
    u64 mn = (a0 < a1) ? a0 : a1;
    u64 mx = (a0 < a1) ? a1 : a0;
    a0 = mn; a1 = mx;
    // odd pass: (item 2i+1, item 2i+2) = (a1[i], a0[i+1])
    u64 up = shfl64_grp(a0, sub + 1);
    u64 dn = shfl64_grp(a1, sub - 1);
    if (sub < 31) a1 = (a1 < up) ? a1 : up;
    if (sub > 0)  a0 = (a0 > dn) ? a0 : dn;
  }
}

__global__ __launch_bounds__(256)
void knn_kernel(const float* __restrict__ x, const float* __restrict__ xyz,
                const void* __restrict__ validp, const int* __restrict__ flagp,
                const float4* __restrict__ pw, u64* __restrict__ wnws, int nseg,
                float* __restrict__ out) {
  __shared__ __align__(16) float4 st[CH];   // 16 KB
  __shared__ u64 buf[SNBLK][BCAP];          // 8 KB candidate buffers
  __shared__ u64 wnl[SNBLK * KNN];          // 2 KB (nseg==1 emit path only)

  const int b = blockIdx.x >> 6;            // 64 sn-blocks per batch
  const int snblk = blockIdx.x & 63;
  const int seg = blockIdx.y;
  const int t = threadIdx.x;
  const int g = t >> 5;
  const int sub = t & 31;
  const int lanebase = t & 32;
  const int m0 = snblk * SNBLK + g * SPG;
  const float* xyzb = xyz + (size_t)b * NPTS * 3;
  const long long gbase = (long long)b * NPTS;
  const int vmode = pw ? 0 : flagp[0];

  float a2x[SPG], a2y[SPG], a2z[SPG];
#pragma unroll
  for (int s = 0; s < SPG; s++) {
    int sidx = (int)out[O3 + (size_t)b * M_SN + m0 + s];
    float ax, ay, az;
    if (pw) { float4 c = pw[gbase + sidx]; ax = c.x; ay = c.y; az = c.z; }
    else { ax = xyzb[3 * sidx]; ay = xyzb[3 * sidx + 1]; az = xyzb[3 * sidx + 2]; }
    a2x[s] = ax + ax; a2y[s] = ay + ay; a2z[s] = az + az;
  }

  const int S = NPTS / nseg;
  const int sbeg = seg * S;

  float thrq[SPG]; int cnt[SPG]; bool virgin[SPG];
#pragma unroll
  for (int s = 0; s < SPG; s++) { thrq[s] = -INFINITY; cnt[s] = 0; virgin[s] = true; }

  for (int c0 = sbeg; c0 < sbeg + S; c0 += CH) {
    // ---- stage CH points into LDS ----
    if (pw) {
      const float4* src = pw + gbase + c0;
#pragma unroll
      for (int qq = 0; qq < CH / NTHR2; qq++) st[t + qq * NTHR2] = src[t + qq * NTHR2];
    } else {
      for (int p = t; p < CH; p += NTHR2) {
        float px = xyzb[3 * (c0 + p)], py = xyzb[3 * (c0 + p) + 1], pz = xyzb[3 * (c0 + p) + 2];
        bool v = is_valid_el(validp, vmode, gbase + c0 + p);
        float sb = __fadd_rn(__fadd_rn(__fmul_rn(px, px), __fmul_rn(py, py)), __fmul_rn(pz, pz));
        st[p] = make_float4(px, py, pz, v ? sb : INFINITY);
      }
    }
    __syncthreads();

#pragma unroll 2
    for (int j = 0; j < CH / 32; j++) {
      float4 v = st[sub + 32 * j];
#pragma unroll
      for (int s = 0; s < SPG; s++) {
        u64* gb = &buf[g * SPG + s][0];
        float qv = __builtin_fmaf(a2x[s], v.x, __builtin_fmaf(a2y[s], v.y, __builtin_fmaf(a2z[s], v.z, -v.w)));
        bool acc = virgin[s] || (qv > thrq[s]);   // strict >: idx-asc arrival => exact ties
        u64 bal = __ballot(acc);
        u32 mq = (u32)(bal >> lanebase);
        if (mq) {                                 // group-uniform
          int na = __popc(mq);
          if (cnt[s] + na > BCAP) {               // group-uniform compact
            u64 a0, a1;
            sort64g(gb, cnt[s], sub, a0, a1);
            if (sub < 8) { gb[2 * sub] = a0; gb[2 * sub + 1] = a1; }
            u64 k15 = shfl64_grp(a1, 7);          // item 15 = exact 16th-best
            thrq[s] = desc_dec((u32)(k15 >> 32));
            cnt[s] = 16;
            virgin[s] = false;
          }
          if (acc) {
            int pos = cnt[s] + __popc(mq & ((1u << sub) - 1u));
            gb[pos] = ((u64)desc_enc(qv) << 32) | (u32)(c0 + 32 * j + sub);
          }
          cnt[s] += na;                           // 16 + 32 <= BCAP always
        }
      }
    }
    __syncthreads();
  }

  // ---- final: sort buffer, emit exact ordered top-16 ----
#pragma unroll
  for (int s = 0; s < SPG; s++) {
    u64 a0, a1;
    sort64g(&buf[g * SPG + s][0], cnt[s], sub, a0, a1);
    if (wnws) {
      size_t base = (((size_t)seg * BF + b) * M_SN + (m0 + s)) * KNN;
      if (sub < 8) { wnws[base + 2 * sub] = a0; wnws[base + 2 * sub + 1] = a1; }
    } else {
      if (sub < 8) { wnl[(g * SPG + s) * KNN + 2 * sub] = a0; wnl[(g * SPG + s) * KNN + 2 * sub + 1] = a1; }
    }
  }
  if (wnws) return;

  // nseg==1 direct-emit fallback
  __syncthreads();
  for (int r = t; r < SNBLK * KNN; r += NTHR2) {
    u64 key = wnl[r];
    int ni = (int)(key & (u64)(NPTS - 1));
    int mm = snblk * SNBLK + (r >> 4);
    size_t o2 = ((size_t)b * M_SN + mm) * KNN + (r & 15);
    out[O2 + o2] = enc_finite((u32)(key >> 32)) ? 1.0f : 0.0f;
    const float4* src = (const float4*)(x + (gbase + ni) * CCH);
    float4* dst = (float4*)(out + O0 + o2 * CCH);
#pragma unroll
    for (int q = 0; q < 16; q++) dst[q] = src[q];
  }
}

// ---------------- K3: merge nseg sorted 16-lists per sn + gather ----------------
// Keys are unique u64 (idx in low bits) -> strict < is a total order -> exact.
#define MSPB 4   // supernodes per merge block
__global__ __launch_bounds__(256)
void knn_merge_kernel(const float* __restrict__ x, const u64* __restrict__ wnws,
                      int nseg, float* __restrict__ out) {
  __shared__ u64 keys[MSPB][64];
  __shared__ u64 wsel[MSPB][KNN];
  const int b = blockIdx.x >> 8;          // 256 blocks per batch
  const int sn0 = (blockIdx.x & 255) * MSPB;
  const int t = threadIdx.x;
  const int s = t >> 6, e = t & 63;
  const int E = nseg * KNN;               // 32 or 64
  if (e < E) {
    int seg = e >> 4, k = e & 15;
    keys[s][e] = wnws[(((size_t)seg * BF + b) * M_SN + sn0 + s) * KNN + k];
  }
  __syncthreads();
  if (e < E) {
    u64 my = keys[s][e];
    int rk = 0;
    for (int j = 0; j < E; j++) rk += (keys[s][j] < my);
    if (rk < KNN) wsel[s][rk] = my;
  }
  __syncthreads();
  {
    int row = t >> 2, q4 = t & 3;         // 64 rows, 4 threads/row
    u64 key = wsel[row >> 4][row & 15];
    int ni = (int)(key & (u64)(NPTS - 1));
    int mm = sn0 + (row >> 4);
    size_t o2 = ((size_t)b * M_SN + mm) * KNN + (row & 15);
    if (q4 == 0) out[O2 + o2] = enc_finite((u32)(key >> 32)) ? 1.0f : 0.0f;
    const float4* src = (const float4*)(x + ((size_t)b * NPTS + ni) * CCH);
    float4* dst = (float4*)(out + O0 + o2 * CCH);
#pragma unroll
    for (int q = 0; q < 4; q++) dst[q4 * 4 + q] = src[q4 * 4 + q];
  }
}

extern "C" void kernel_launch(void* const* d_in, const int* in_sizes, int n_in,
                              void* d_out, int out_size, void* d_ws, size_t ws_size,
                              hipStream_t stream) {
  const float* x = (const float*)d_in[0];
  const float* xyz = (const float*)d_in[1];
  const void* valid = d_in[2];
  const float* state = (const float*)d_in[3];
  const int* mask_id = (const int*)d_in[4];
  const float* extra = (const float*)d_in[5];
  const float* glob = (const float*)d_in[6];
  float* out = (float*)d_out;
  int* flag = (int*)d_ws;
  const int vwords = in_sizes[2] / 4;

  float4* pw = nullptr;
  u64* wnws = nullptr;
  int nseg = 1;
  if (ws_size >= PW_OFF + PW_BYTES) pw = (float4*)((char*)d_ws + PW_OFF);
  if (pw && ws_size >= PW_OFF + PW_BYTES + 2 * SEG1_BYTES) {
    nseg = 2; wnws = (u64*)((char*)d_ws + PW_OFF + PW_BYTES);
  }

  if (!pw)   // only the knn !pw fallback needs the flag buffer
    detect_valid<<<1, 1024, 0, stream>>>((const unsigned*)valid, vwords, flag);
  sample_kernel<<<BF, NTHR1, 0, stream>>>(xyz, valid, state, mask_id, extra, glob,
                                          vwords, pw, out);
  dim3 kg(BF * 64, nseg);
  knn_kernel<<<kg, NTHR2, 0, stream>>>(x, xyz, valid, flag, pw, wnws, nseg, out);
  if (nseg > 1) knn_merge_kernel<<<BF * 256, NTHR2, 0, stream>>>(x, wnws, nseg, out);
}

// Round 8
// 264.947 us; speedup vs baseline: 1.3501x; 1.3501x over previous
//
#include <hip/hip_runtime.h>
#include <math.h>

typedef unsigned long long u64;
typedef unsigned int u32;

#define BF 8
#define NPTS 16384
#define HALFPTS 8192
#define M_SN 1024
#define CCH 64
#define KNN 16
#define NTHR1 1024
#define KPER 16            // NPTS / NTHR1
#define TBL 4096
#define CCAP 2048
#define REM 1008           // M - 16 gripper slots

// output layout (flat float32, concatenated in return order)
constexpr size_t O0 = 0;                 // neighbor_feats 8*1024*16*64
constexpr size_t O1 = 8388608;           // supernode_xyz 8*1024*3
constexpr size_t O2 = 8413184;           // neighbor_mask 8*1024*16
constexpr size_t O3 = 8544256;           // out_idx 8*1024
constexpr size_t O4 = 8552448;           // out_valid 8*1024
constexpr size_t O5 = 8560640;           // out_bucket 8*1024

// workspace layout: [0]=flag, PW_OFF: packed float4 points, then split wn lists
#define PW_OFF ((size_t)256)
#define PW_BYTES ((size_t)BF * NPTS * 16)          // 2 MiB
#define WN_BYTES ((size_t)2 * BF * M_SN * KNN * 8) // 2 MiB

__device__ __forceinline__ bool is_valid_el(const void* vp, int mode, long long i) {
  if (mode == 1) return ((const unsigned char*)vp)[i] != 0;
  if (mode == 2) return ((const float*)vp)[i] != 0.0f;
  return ((const int*)vp)[i] != 0;
}

// monotone-decreasing encode: larger float -> smaller u32 (NaN sorts first; -inf last)
__device__ __forceinline__ u32 desc_enc(float f) {
  u32 u = __float_as_uint(f);
  u32 s = (u & 0x80000000u) ? ~u : (u | 0x80000000u);
  return ~s;
}
__device__ __forceinline__ bool enc_finite(u32 d) {
  u32 s = ~d;
  u32 u = (s & 0x80000000u) ? (s & 0x7FFFFFFFu) : ~s;
  return (u & 0x7F800000u) != 0x7F800000u;
}

__device__ __forceinline__ u64 wave_min_u64(u64 v) {
#pragma unroll
  for (int d = 32; d >= 1; d >>= 1) {
    u32 lo = __shfl_xor((u32)(v & 0xFFFFFFFFu), d, 64);
    u32 hi = __shfl_xor((u32)(v >> 32), d, 64);
    u64 o = ((u64)hi << 32) | lo;
    if (o < v) v = o;
  }
  return v;
}

__device__ __forceinline__ u64 block_min_u64(u64 v, u64* red16, int t) {
  v = wave_min_u64(v);
  if ((t & 63) == 0) red16[t >> 6] = v;
  __syncthreads();
  if (t < 64) {
    u64 x = red16[t & 15];
    x = wave_min_u64(x);
    if (t == 0) red16[0] = x;
  }
  __syncthreads();
  u64 r = red16[0];
  __syncthreads();
  return r;
}

__device__ __forceinline__ int block_excl_scan(int val, int* scanb, int t, int* tot) {
  int incl = val;
#pragma unroll
  for (int d = 1; d < 64; d <<= 1) {
    int v = __shfl_up(incl, d, 64);
    if ((t & 63) >= d) incl += v;
  }
  if ((t & 63) == 63) scanb[t >> 6] = incl;
  __syncthreads();
  if (t < 64) {
    int ws = (t < 16) ? scanb[t] : 0;
#pragma unroll
    for (int d = 1; d < 16; d <<= 1) {
      int v = __shfl_up(ws, d, 64);
      if ((t & 63) >= d) ws += v;
    }
    if (t < 16) scanb[16 + t] = ws;
  }
  __syncthreads();
  int wv = t >> 6;
  int base = (wv == 0) ? 0 : scanb[16 + wv - 1];
  *tot = scanb[16 + 15];
  int r = base + incl - val;
  __syncthreads();
  return r;
}

__device__ __forceinline__ u64 shfl64_grp(u64 v, int src) {   // width-32 partitioned
  u32 lo = (u32)__shfl((int)(u32)(v & 0xFFFFFFFFu), src, 32);
  u32 hi = (u32)__shfl((int)(u32)(v >> 32), src, 32);
  return ((u64)hi << 32) | lo;
}

// ---------------------------------------------------------------------------
// topk_select: exact ordered top-T of (ek asc, idx asc) among cmask candidates.
// ---------------------------------------------------------------------------
template<bool ASC, bool SHIFTBIN>
__device__ __forceinline__ void topk_select(const u32* ek, const u32* bk, u32 cmask,
    int Twant, int* table, u64* cand, int* scanb, int* sh, int* outArr, int t) {
  for (int j = t; j < TBL; j += NTHR1) table[j] = 0;
  if (t == 6) sh[6] = 0x7FFFFFFF;
  if (t == 7) sh[7] = 1;
  __syncthreads();
#pragma unroll
  for (int k = 0; k < KPER; k++) {
    if ((cmask >> k) & 1u) {
      int bin = SHIFTBIN ? (int)(ek[k] >> 20) : (int)bk[k];
      atomicAdd(&table[bin], 1);
    }
  }
  __syncthreads();
  int c_[4]; int c4 = 0;
#pragma unroll
  for (int q = 0; q < 4; q++) { c_[q] = table[4 * t + q]; c4 += c_[q]; }
  int htot;
  int cum = block_excl_scan(c4, scanb, t, &htot);
  const int T = min(Twant, htot);
  int e_ = cum;
#pragma unroll
  for (int q = 0; q < 4; q++) {
    int nx = e_ + c_[q];
    if (T > 0 && e_ < T && nx >= T) atomicMin(&sh[6], 4 * t + q);
    table[4 * t + q] = e_;           // overwrite counts with exclusive cums
    e_ = nx;
  }
  __syncthreads();
  if (T <= 0) return;                // uniform; outArr stays -1; sh[7] stays 1
  const int B = sh[6];
#pragma unroll
  for (int k = 0; k < KPER; k++) {
    if ((cmask >> k) & 1u) {
      int bin = SHIFTBIN ? (int)(ek[k] >> 20) : (int)bk[k];
      if (bin <= B) {
        int pos = atomicAdd(&table[bin], 1);   // grouped placement per bin
        if (pos < CCAP)
          cand[pos] = ((u64)ek[k] << 32) | ((u64)(u32)bin << 14) | (u32)(k * NTHR1 + t);
      }
    }
  }
  __syncthreads();
  const int nc = table[B];           // inclusive end of bin B == total collected
  if (nc <= CCAP) {
    for (int c = t; c < nc; c += NTHR1) {
      u64 key = cand[c];
      int bin = (int)((key >> 14) & 0xFFFu);
      int s = bin ? table[bin - 1] : 0;        // segment start (end of bin-1)
      int e2 = table[bin];                     // segment end
      int r = s;
      for (int j = s; j < e2; j++) r += (cand[j] < key);
      if (r < T) {
        u32 enc = (u32)(key >> 32);
        int ix = (int)(key & 0x3FFFu);
        bool fin = ASC ? (enc < 0x7F800000u) : enc_finite(enc);
        outArr[r] = fin ? ix : (ix | (int)0x80000000);
      }
    }
  } else {
    if (t == 0) sh[7] = 0;
  }
  __syncthreads();
}

// ---------------- K0: detect how `valid` (bool) is stored ----------------
// 64-block grid-stride + atomicMax into pre-zeroed flag (memset on host side).
__global__ void detect_valid(const unsigned* __restrict__ w, int nwords, int* __restrict__ flag) {
  int local = 0;
  for (int i = blockIdx.x * blockDim.x + threadIdx.x; i < nwords; i += gridDim.x * blockDim.x) {
    unsigned v = w[i];
    if (v == 0x3F800000u) local = 2;            // float32 storage
    else if (v != 0u && v != 1u) local = max(local, 1); // packed bytes
  }
#pragma unroll
  for (int d = 32; d >= 1; d >>= 1) local = max(local, __shfl_xor(local, d, 64));
  if ((threadIdx.x & 63) == 0 && local) atomicMax(flag, local);
}

// ---------------- K1: supernode sampling (one block per batch row) ----------------
__global__ __launch_bounds__(1024)
void sample_kernel(const float* __restrict__ xyz, const void* __restrict__ validp,
                   const float* __restrict__ state, const int* __restrict__ mask_id,
                   const float* __restrict__ extra, const float* __restrict__ glob,
                   const int* __restrict__ flagp, float4* __restrict__ pw,
                   float* __restrict__ out) {
  __shared__ u64 red16[16];
  __shared__ int table[TBL];        // 16 KB
  __shared__ int scanb[32];
  __shared__ int mpick[REM];
  __shared__ u64 cand[CCAP];        // 16 KB
  __shared__ int gsorted[REM];
  __shared__ int head_i[16];
  __shared__ int head_bk[16];
  __shared__ int sh[8];             // 0:rhv 1:first_valid 2:has_radius 6:B 7:ok

  const int b = blockIdx.x, t = threadIdx.x;
  const int vmode = flagp[0];
  const float* xyzb = xyz + (size_t)b * NPTS * 3;
  const int* midb = mask_id + (size_t)b * NPTS;
  const float* exb = extra + (size_t)b * NPTS;
  const float* glb = glob + (size_t)b * NPTS;

  if (t < 8) sh[t] = 0;
  if (t == 1) sh[1] = 0x7FFFFFFF;
  if (t < 16) gsorted[t] = -1;      // gripper winners default
  __syncthreads();

  // ---- validity bits (element i = k*1024 + t) ----
  u32 vbits = 0;
#pragma unroll
  for (int k = 0; k < KPER; k++) {
    int i = k * NTHR1 + t;
    if (is_valid_el(validp, vmode, (long long)b * NPTS + i)) vbits |= 1u << k;
  }
  if (vbits) {
    atomicOr(&sh[0], 1);
    atomicMin(&sh[1], (__ffs(vbits) - 1) * NTHR1 + t);
  }

  // ---- gripper distances + packed point array for knn ----
  float gx = state[b * 8 + 0], gy = state[b * 8 + 1], gz = state[b * 8 + 2];
  float gd[KPER];
  u32 inr = 0;
#pragma unroll
  for (int k = 0; k < KPER; k++) {
    int i = k * NTHR1 + t;
    float px = xyzb[3 * i], py = xyzb[3 * i + 1], pz = xyzb[3 * i + 2];
    float dx = px - gx, dy = py - gy, dz = pz - gz;
    float d = sqrtf((dx * dx + dy * dy) + dz * dz);
    gd[k] = d;
    bool vb = (vbits >> k) & 1u;
    if (vb && d <= 0.1f) inr |= 1u << k;
    if (pw) {
      float sb = __fadd_rn(__fadd_rn(__fmul_rn(px, px), __fmul_rn(py, py)), __fmul_rn(pz, pz));
      pw[(size_t)b * NPTS + i] = make_float4(px, py, pz, vb ? sb : INFINITY);
    }
  }
  if (inr) atomicOr(&sh[2], 1);
  __syncthreads();

  const int rhv = sh[0];
  const int first_valid = rhv ? sh[1] : 0;
  const u32 elig = vbits & (sh[2] ? inr : 0xFFFFu);
  u32 sel = 0;

  // ---- gripper: exact ordered top-16 of (gdist asc, idx asc) over eligible ----
  {
    u32 ek[KPER];
#pragma unroll
    for (int k = 0; k < KPER; k++) ek[k] = __float_as_uint(gd[k]);  // gd>=0: bits asc
    topk_select<true, true>(ek, nullptr, elig, 16, table, cand, scanb, sh, gsorted, t);
    if (sh[7]) {
      if (t < 16) {
        int g = gsorted[t];
        head_i[t] = (g >= 0) ? g : first_valid;
        head_bk[t] = (g >= 0) ? 1 : -1;
      }
      __syncthreads();
      for (int j = 0; j < 16; j++) {
        if (head_bk[j] == 1) {
          int ix = head_i[j];
          if ((ix & (NTHR1 - 1)) == t) sel |= 1u << (ix >> 10);
        }
      }
    } else {
      // pathological-ties fallback: iterative extraction
      for (int it = 0; it < 16; ++it) {
        u64 best = ~0ull;
#pragma unroll
        for (int k = 0; k < KPER; k++) {
          if (((elig >> k) & 1u) && !((sel >> k) & 1u)) {
            u64 key = ((u64)__float_as_uint(gd[k]) << 32) | (u32)(k * NTHR1 + t);
            if (key < best) best = key;
          }
        }
        u64 w = block_min_u64(best, red16, t);
        bool keep = (w >> 32) < 0x7F800000ull;
        int idx = (int)(w & 0xFFFFFFFFu);
        if (t == 0) { head_i[it] = keep ? idx : first_valid; head_bk[it] = keep ? 1 : -1; }
        if (keep && (idx & (NTHR1 - 1)) == t) sel |= 1u << (idx >> 10);
      }
      __syncthreads();
    }
  }

  // ---- mask stage: min index per distinct mask_id among candidates ----
  for (int j = t; j < TBL; j += NTHR1) table[j] = 0x7FFFFFFF;
  __syncthreads();
#pragma unroll
  for (int k = 0; k < KPER; k++) {
    if (((vbits >> k) & 1u) && !((sel >> k) & 1u)) {
      int i = k * NTHR1 + t;
      int id = midb[i];
      if ((u32)id < TBL) atomicMin(&table[id], i);
    }
  }
  __syncthreads();
  int cnt = 0;
#pragma unroll
  for (int q = 0; q < 4; q++) cnt += (table[4 * t + q] != 0x7FFFFFFF);
  int mtot;
  int excl = block_excl_scan(cnt, scanb, t, &mtot);
  {
    int pos = excl;
#pragma unroll
    for (int q = 0; q < 4; q++) {
      int v = table[4 * t + q];
      if (v != 0x7FFFFFFF) { if (pos < REM) mpick[pos] = v; pos++; }
    }
  }
  __syncthreads();
  const int nm = min(mtot, REM);
  for (int j = 0; j < nm; j++) {
    int p = mpick[j];
    if ((p & (NTHR1 - 1)) == t) sel |= 1u << (p >> 10);
  }

  // ---- extra stage (only active when < 8 distinct mask ids) ----
  u32 extra_used = 0;
  if (nm < 8 && rhv) {
    u32 extrbits = 0;
    for (int j = 0; j < 8; j++) {
      u64 best = ~0ull;
#pragma unroll
      for (int k = 0; k < KPER; k++) {
        if (((vbits >> k) & 1u) && !((sel >> k) & 1u) && !((extrbits >> k) & 1u)) {
          int i = k * NTHR1 + t;
          u64 key = ((u64)desc_enc(exb[i]) << 32) | (u32)i;
          if (key < best) best = key;
        }
      }
      u64 w = block_min_u64(best, red16, t);
      if (w == ~0ull) break;
      int idx = (int)(w & 0xFFFFFFFFu);
      bool fin = enc_finite((u32)(w >> 32));
      if ((idx & (NTHR1 - 1)) == t) extrbits |= 1u << (idx >> 10);
      if (j >= nm && fin) {
        extra_used |= 1u << j;
        if (t == 0) mpick[j] = idx;
        if ((idx & (NTHR1 - 1)) == t) sel |= 1u << (idx >> 10);
      }
    }
    __syncthreads();
  }

  // ---- global stage: exact ordered top-1008 of (global_score desc, idx asc) ----
  {
    u32 cbits = vbits & ~sel;
    u32 ek[KPER], bk[KPER];
#pragma unroll
    for (int k = 0; k < KPER; k++) {
      if ((cbits >> k) & 1u) {
        float f = glb[k * NTHR1 + t];
        ek[k] = desc_enc(f);
        float g = fminf(fmaxf(f, 0.0f), 0.99999994f);
        bk[k] = 4095u - (u32)(g * 4096.0f);
      } else { ek[k] = 0xFFFFFFFFu; bk[k] = 4095u; }
    }
    for (int j = t; j < REM; j += NTHR1) gsorted[j] = -1;
    topk_select<false, false>(ek, bk, cbits, REM, table, cand, scanb, sh, gsorted, t);
    if (!sh[7]) {
      u32 gext = 0;
      for (int j = 0; j < REM; j++) {
        u64 best = ~0ull;
#pragma unroll
        for (int k = 0; k < KPER; k++) {
          if (((cbits >> k) & 1u) && !((gext >> k) & 1u)) {
            u64 key = ((u64)ek[k] << 32) | (u32)(k * NTHR1 + t);
            if (key < best) best = key;
          }
        }
        u64 w = block_min_u64(best, red16, t);
        if (w == ~0ull) break;
        int idx = (int)(w & 0xFFFFFFFFu);
        if ((idx & (NTHR1 - 1)) == t) gext |= 1u << (idx >> 10);
        if (t == 0) gsorted[j] = enc_finite((u32)(w >> 32)) ? idx : (idx | (int)0x80000000);
      }
      __syncthreads();
    }
  }

  // ---- emit out_idx / out_valid / out_bucket / supernode_xyz ----
  {
    int slot = t;
    int idx, bucket;
    if (slot < 16) {
      idx = head_i[slot];
      bucket = head_bk[slot];
    } else {
      int jj = slot - 16;
      bool mk = (jj < nm) || (jj < 8 && ((extra_used >> jj) & 1u));
      if (mk) { idx = mpick[jj]; bucket = 2; }
      else {
        int g = gsorted[jj];
        if (rhv && g >= 0) { idx = g; bucket = 0; }
        else { idx = first_valid; bucket = -1; }
      }
    }
    bool ov = rhv && is_valid_el(validp, vmode, (long long)b * NPTS + idx);
    int ob = ov ? bucket : -1;
    size_t o = (size_t)b * M_SN + slot;
    out[O3 + o] = (float)idx;
    out[O4 + o] = ov ? 1.0f : 0.0f;
    out[O5 + o] = (float)ob;
    out[O1 + 3 * o + 0] = xyzb[3 * idx + 0];
    out[O1 + 3 * o + 1] = xyzb[3 * idx + 1];
    out[O1 + 3 * o + 2] = xyzb[3 * idx + 2];
  }
}

// ---------------- K2: KNN-16 distance scan (R1 structure, proven 137us) ----------------
// 8 supernodes per 256-thr block, 1 per 32-lane group; LDS-staged CH=1024 chunks;
// immediate ballot + 3-shuffle distributed sorted insert. Hot-loop deltas vs R1:
// q = 2a.b - |b|^2 via 3 FMA (maximize q <=> minimize d2; validated R3-R6) and a
// seed sort for chunk 0 (kills ~40 cold-start insert events; validated R3-R6).
#define NTHR2 256
#define CH 1024
#define SPB 8

__global__ __launch_bounds__(256, 8)
void knn_kernel(const float* __restrict__ x, const float* __restrict__ xyz,
                const void* __restrict__ validp, const int* __restrict__ flagp,
                const float4* __restrict__ pw, u64* __restrict__ wnws,
                float* __restrict__ out) {
  __shared__ __align__(16) float4 st[CH];           // 16 KB
  __shared__ u64 wn[SPB * KNN];                     // 1 KB

  const int b = blockIdx.x >> 7;
  const int grp = blockIdx.x & 127;
  const int half = blockIdx.y;
  const int t = threadIdx.x;
  const int sl = t >> 5;
  const int sub = t & 31;
  const int lanebase = t & 32;
  const int m = grp * SPB + sl;
  const float* xyzb = xyz + (size_t)b * NPTS * 3;
  const long long gbase = (long long)b * NPTS;

  const int sidx = (int)out[O3 + (size_t)b * M_SN + m];
  float ax, ay, az;
  if (pw) { float4 c = pw[gbase + sidx]; ax = c.x; ay = c.y; az = c.z; }
  else { ax = xyzb[3 * sidx]; ay = xyzb[3 * sidx + 1]; az = xyzb[3 * sidx + 2]; }
  const float a2x = ax + ax, a2y = ay + ay, a2z = az + az;

  float ld = -INFINITY;   // lane sub = sub-th LARGEST q seen so far
  int li = 0;
  float kq = -INFINITY;   // group 16th-largest q (replicated)

  const int vmode = pw ? 0 : flagp[0];
  const int cbeg = wnws ? half * HALFPTS : 0;
  const int cend = wnws ? cbeg + HALFPTS : NPTS;

  for (int c0 = cbeg; c0 < cend; c0 += CH) {
    if (pw) {
      const float4* src = pw + gbase + c0;
#pragma unroll
      for (int qq = 0; qq < CH / NTHR2; qq++) st[t + qq * NTHR2] = src[t + qq * NTHR2];
    } else {
      for (int p = t; p < CH; p += NTHR2) {
        float px = xyzb[3 * (c0 + p)], py = xyzb[3 * (c0 + p) + 1], pz = xyzb[3 * (c0 + p) + 2];
        bool v = is_valid_el(validp, vmode, gbase + c0 + p);
        float sb = __fadd_rn(__fadd_rn(__fmul_rn(px, px), __fmul_rn(py, py)), __fmul_rn(pz, pz));
        st[p] = make_float4(px, py, pz, v ? sb : INFINITY);
      }
    }
    __syncthreads();

    int jstart = 0;
    if (c0 == cbeg) {
      // seed: stable descending sort of first 32 points' (q, idx) across lanes
      float4 v = st[sub];
      float qv = __builtin_fmaf(a2x, v.x, __builtin_fmaf(a2y, v.y, __builtin_fmaf(a2z, v.z, -v.w)));
      int qi = c0 + sub;
#pragma unroll
      for (int p = 0; p < 32; p++) {
        int par;
        if ((p & 1) == 0) par = sub ^ 1;
        else par = (sub == 0 || sub == 31) ? sub : (((sub - 1) ^ 1) + 1);
        float oq = __shfl(qv, par, 32);
        int oi = __shfl(qi, par, 32);
        if (par != sub) {
          bool lo = sub < par;
          bool take = lo ? (oq > qv) : (oq < qv);   // strict -> stable (idx asc on ties)
          if (take) { qv = oq; qi = oi; }
        }
      }
      ld = qv; li = qi;
      kq = __shfl(ld, 15, 32);
      jstart = 1;
    }

#pragma unroll 4
    for (int j = jstart; j < CH / 32; j++) {
      float4 v = st[sub + 32 * j];
      float qv = __builtin_fmaf(a2x, v.x, __builtin_fmaf(a2y, v.y, __builtin_fmaf(a2z, v.z, -v.w)));
      u64 bal = __ballot(qv > kq);
      u32 mq = (u32)(bal >> lanebase);
      while (mq) {
        int bb = __ffs(mq) - 1;
        mq &= mq - 1;
        float kd = __shfl(qv, lanebase + bb, 64);
        if (kd > kq) {                        // group-uniform re-check (kq tightened)
          int ki = c0 + 32 * j + bb;
          bool gt = ld < kd;
          float sd = __shfl_up(ld, 1, 32);
          int si = __shfl_up(li, 1, 32);
          int pg = __shfl_up(gt ? 1 : 0, 1, 32);
          if (sub == 0) pg = 0;
          ld = gt ? (pg ? sd : kd) : ld;
          li = gt ? (pg ? si : ki) : li;
          kq = __shfl(ld, 15, 32);
        }
      }
    }
    __syncthreads();
  }

  if (wnws) {
    if (sub < KNN)
      wnws[((size_t)half * BF + b) * M_SN * KNN + (size_t)m * KNN + sub] =
          ((u64)desc_enc(ld) << 32) | (u32)li;
    return;
  }

  // non-split fallback: emit directly
  if (sub < KNN) wn[sl * KNN + sub] = ((u64)desc_enc(ld) << 32) | (u32)li;
  __syncthreads();
  {
    int s2 = t >> 5;
    int k2 = (t >> 1) & 15;
    int hf = t & 1;
    int mm = grp * SPB + s2;
    u64 key = wn[s2 * KNN + k2];
    int ni = (int)(key & (u64)(NPTS - 1));
    size_t o2 = ((size_t)b * M_SN + mm) * KNN + k2;
    if (hf == 0) out[O2 + o2] = enc_finite((u32)(key >> 32)) ? 1.0f : 0.0f;
    const float4* src = (const float4*)(x + (gbase + ni) * CCH);
    float4* dst = (float4*)(out + O0 + o2 * CCH);
#pragma unroll
    for (int q = 0; q < 8; q++) dst[hf * 8 + q] = src[hf * 8 + q];
  }
}

// ---------------- K3: merge the two half-range top-16 lists + emit ----------------
__global__ __launch_bounds__(256)
void knn_merge_kernel(const float* __restrict__ x, const u64* __restrict__ wnws,
                      float* __restrict__ out) {
  __shared__ u64 wn[SPB * KNN];
  const int b = blockIdx.x >> 7;
  const int grp = blockIdx.x & 127;
  const int t = threadIdx.x;
  const int sl = t >> 5;
  const int sub = t & 31;
  const int m = grp * SPB + sl;

  // lanes 0-15: half0 list, lanes 16-31: half1 list (each sorted ascending by key)
  const int h = sub >> 4, k = sub & 15;
  u64 my = wnws[((size_t)h * BF + b) * M_SN * KNN + (size_t)m * KNN + k];
  const int obase = (1 - h) << 4;
  int cnt2 = 0;
#pragma unroll
  for (int j = 0; j < 16; j++) {
    u64 o = shfl64_grp(my, obase + j);
    cnt2 += h ? (o <= my) : (o < my);   // stable merge: half0 wins ties
  }
  int rank = k + cnt2;
  if (rank < KNN) wn[sl * KNN + rank] = my;
  __syncthreads();

  {
    int s2 = t >> 5;
    int k2 = (t >> 1) & 15;
    int hf = t & 1;
    int mm = grp * SPB + s2;
    u64 key = wn[s2 * KNN + k2];
    int ni = (int)(key & (u64)(NPTS - 1));
    size_t o2 = ((size_t)b * M_SN + mm) * KNN + k2;
    if (hf == 0) out[O2 + o2] = enc_finite((u32)(key >> 32)) ? 1.0f : 0.0f;
    const float4* src = (const float4*)(x + ((size_t)b * NPTS + ni) * CCH);
    float4* dst = (float4*)(out + O0 + o2 * CCH);
#pragma unroll
    for (int q = 0; q < 8; q++) dst[hf * 8 + q] = src[hf * 8 + q];
  }
}

extern "C" void kernel_launch(void* const* d_in, const int* in_sizes, int n_in,
                              void* d_out, int out_size, void* d_ws, size_t ws_size,
                              hipStream_t stream) {
  const float* x = (const float*)d_in[0];
  const float* xyz = (const float*)d_in[1];
  const void* valid = d_in[2];
  const float* state = (const float*)d_in[3];
  const int* mask_id = (const int*)d_in[4];
  const float* extra = (const float*)d_in[5];
  const float* glob = (const float*)d_in[6];
  float* out = (float*)d_out;
  int* flag = (int*)d_ws;

  float4* pw = nullptr;
  u64* wnws = nullptr;
  if (ws_size >= PW_OFF + PW_BYTES) pw = (float4*)((char*)d_ws + PW_OFF);
  if (pw && ws_size >= PW_OFF + PW_BYTES + WN_BYTES)
    wnws = (u64*)((char*)d_ws + PW_OFF + PW_BYTES);

  // Runtime storage probe (proven; NEVER infer from in_sizes -- broke out_idx in R2).
  hipMemsetAsync(flag, 0, 4, stream);
  detect_valid<<<64, 1024, 0, stream>>>((const unsigned*)valid, in_sizes[2] / 4, flag);
  sample_kernel<<<BF, NTHR1, 0, stream>>>(xyz, valid, state, mask_id, extra, glob, flag, pw, out);
  dim3 kg(BF * 128, wnws ? 2 : 1);
  knn_kernel<<<kg, NTHR2, 0, stream>>>(x, xyz, valid, flag, pw, wnws, out);
  if (wnws) knn_merge_kernel<<<BF * 128, NTHR2, 0, stream>>>(x, wnws, out);
}

// Round 9
// 261.124 us; speedup vs baseline: 1.3699x; 1.0146x over previous
//
#include <hip/hip_runtime.h>
#include <math.h>

typedef unsigned long long u64;
typedef unsigned int u32;

#define BF 8
#define NPTS 16384
#define HALFPTS 8192
#define M_SN 1024
#define CCH 64
#define KNN 16
#define NTHR1 1024
#define KPER 16            // NPTS / NTHR1
#define TBL 4096
#define CCAP 2048
#define REM 1008           // M - 16 gripper slots

// output layout (flat float32, concatenated in return order)
constexpr size_t O0 = 0;                 // neighbor_feats 8*1024*16*64
constexpr size_t O1 = 8388608;           // supernode_xyz 8*1024*3
constexpr size_t O2 = 8413184;           // neighbor_mask 8*1024*16
constexpr size_t O3 = 8544256;           // out_idx 8*1024
constexpr size_t O4 = 8552448;           // out_valid 8*1024
constexpr size_t O5 = 8560640;           // out_bucket 8*1024

// workspace layout: [0]=flag, PW_OFF: packed float4 points, then split wn lists
#define PW_OFF ((size_t)256)
#define PW_BYTES ((size_t)BF * NPTS * 16)          // 2 MiB
#define WN_BYTES ((size_t)2 * BF * M_SN * KNN * 8) // 2 MiB

__device__ __forceinline__ bool is_valid_el(const void* vp, int mode, long long i) {
  if (mode == 1) return ((const unsigned char*)vp)[i] != 0;
  if (mode == 2) return ((const float*)vp)[i] != 0.0f;
  return ((const int*)vp)[i] != 0;
}

// monotone-decreasing encode: larger float -> smaller u32 (NaN sorts first; -inf last)
__device__ __forceinline__ u32 desc_enc(float f) {
  u32 u = __float_as_uint(f);
  u32 s = (u & 0x80000000u) ? ~u : (u | 0x80000000u);
  return ~s;
}
__device__ __forceinline__ float desc_dec(u32 e) {   // exact inverse of desc_enc
  u32 s = ~e;
  u32 u = (s & 0x80000000u) ? (s & 0x7FFFFFFFu) : ~s;
  return __uint_as_float(u);
}
__device__ __forceinline__ bool enc_finite(u32 d) {
  u32 s = ~d;
  u32 u = (s & 0x80000000u) ? (s & 0x7FFFFFFFu) : ~s;
  return (u & 0x7F800000u) != 0x7F800000u;
}

__device__ __forceinline__ u64 wave_min_u64(u64 v) {
#pragma unroll
  for (int d = 32; d >= 1; d >>= 1) {
    u32 lo = __shfl_xor((u32)(v & 0xFFFFFFFFu), d, 64);
    u32 hi = __shfl_xor((u32)(v >> 32), d, 64);
    u64 o = ((u64)hi << 32) | lo;
    if (o < v) v = o;
  }
  return v;
}

__device__ __forceinline__ u64 block_min_u64(u64 v, u64* red16, int t) {
  v = wave_min_u64(v);
  if ((t & 63) == 0) red16[t >> 6] = v;
  __syncthreads();
  if (t < 64) {
    u64 x = red16[t & 15];
    x = wave_min_u64(x);
    if (t == 0) red16[0] = x;
  }
  __syncthreads();
  u64 r = red16[0];
  __syncthreads();
  return r;
}

__device__ __forceinline__ int block_excl_scan(int val, int* scanb, int t, int* tot) {
  int incl = val;
#pragma unroll
  for (int d = 1; d < 64; d <<= 1) {
    int v = __shfl_up(incl, d, 64);
    if ((t & 63) >= d) incl += v;
  }
  if ((t & 63) == 63) scanb[t >> 6] = incl;
  __syncthreads();
  if (t < 64) {
    int ws = (t < 16) ? scanb[t] : 0;
#pragma unroll
    for (int d = 1; d < 16; d <<= 1) {
      int v = __shfl_up(ws, d, 64);
      if ((t & 63) >= d) ws += v;
    }
    if (t < 16) scanb[16 + t] = ws;
  }
  __syncthreads();
  int wv = t >> 6;
  int base = (wv == 0) ? 0 : scanb[16 + wv - 1];
  *tot = scanb[16 + 15];
  int r = base + incl - val;
  __syncthreads();
  return r;
}

__device__ __forceinline__ u64 shfl64_grp(u64 v, int src) {   // width-32 partitioned
  u32 lo = (u32)__shfl((int)(u32)(v & 0xFFFFFFFFu), src, 32);
  u32 hi = (u32)__shfl((int)(u32)(v >> 32), src, 32);
  return ((u64)hi << 32) | lo;
}

// ---------------------------------------------------------------------------
// topk_select: exact ordered top-T of (ek asc, idx asc) among cmask candidates.
// ---------------------------------------------------------------------------
template<bool ASC, bool SHIFTBIN>
__device__ __forceinline__ void topk_select(const u32* ek, const u32* bk, u32 cmask,
    int Twant, int* table, u64* cand, int* scanb, int* sh, int* outArr, int t) {
  for (int j = t; j < TBL; j += NTHR1) table[j] = 0;
  if (t == 6) sh[6] = 0x7FFFFFFF;
  if (t == 7) sh[7] = 1;
  __syncthreads();
#pragma unroll
  for (int k = 0; k < KPER; k++) {
    if ((cmask >> k) & 1u) {
      int bin = SHIFTBIN ? (int)(ek[k] >> 20) : (int)bk[k];
      atomicAdd(&table[bin], 1);
    }
  }
  __syncthreads();
  int c_[4]; int c4 = 0;
#pragma unroll
  for (int q = 0; q < 4; q++) { c_[q] = table[4 * t + q]; c4 += c_[q]; }
  int htot;
  int cum = block_excl_scan(c4, scanb, t, &htot);
  const int T = min(Twant, htot);
  int e_ = cum;
#pragma unroll
  for (int q = 0; q < 4; q++) {
    int nx = e_ + c_[q];
    if (T > 0 && e_ < T && nx >= T) atomicMin(&sh[6], 4 * t + q);
    table[4 * t + q] = e_;           // overwrite counts with exclusive cums
    e_ = nx;
  }
  __syncthreads();
  if (T <= 0) return;                // uniform; outArr stays -1; sh[7] stays 1
  const int B = sh[6];
#pragma unroll
  for (int k = 0; k < KPER; k++) {
    if ((cmask >> k) & 1u) {
      int bin = SHIFTBIN ? (int)(ek[k] >> 20) : (int)bk[k];
      if (bin <= B) {
        int pos = atomicAdd(&table[bin], 1);   // grouped placement per bin
        if (pos < CCAP)
          cand[pos] = ((u64)ek[k] << 32) | ((u64)(u32)bin << 14) | (u32)(k * NTHR1 + t);
      }
    }
  }
  __syncthreads();
  const int nc = table[B];           // inclusive end of bin B == total collected
  if (nc <= CCAP) {
    for (int c = t; c < nc; c += NTHR1) {
      u64 key = cand[c];
      int bin = (int)((key >> 14) & 0xFFFu);
      int s = bin ? table[bin - 1] : 0;        // segment start (end of bin-1)
      int e2 = table[bin];                     // segment end
      int r = s;
      for (int j = s; j < e2; j++) r += (cand[j] < key);
      if (r < T) {
        u32 enc = (u32)(key >> 32);
        int ix = (int)(key & 0x3FFFu);
        bool fin = ASC ? (enc < 0x7F800000u) : enc_finite(enc);
        outArr[r] = fin ? ix : (ix | (int)0x80000000);
      }
    }
  } else {
    if (t == 0) sh[7] = 0;
  }
  __syncthreads();
}

// ---------------- K0: detect how `valid` (bool) is stored ----------------
// 64-block grid-stride + atomicMax into pre-zeroed flag (memset on host side).
__global__ void detect_valid(const unsigned* __restrict__ w, int nwords, int* __restrict__ flag) {
  int local = 0;
  for (int i = blockIdx.x * blockDim.x + threadIdx.x; i < nwords; i += gridDim.x * blockDim.x) {
    unsigned v = w[i];
    if (v == 0x3F800000u) local = 2;            // float32 storage
    else if (v != 0u && v != 1u) local = max(local, 1); // packed bytes
  }
#pragma unroll
  for (int d = 32; d >= 1; d >>= 1) local = max(local, __shfl_xor(local, d, 64));
  if ((threadIdx.x & 63) == 0 && local) atomicMax(flag, local);
}

// ---------------- K1: supernode sampling (one block per batch row) ----------------
__global__ __launch_bounds__(1024)
void sample_kernel(const float* __restrict__ xyz, const void* __restrict__ validp,
                   const float* __restrict__ state, const int* __restrict__ mask_id,
                   const float* __restrict__ extra, const float* __restrict__ glob,
                   const int* __restrict__ flagp, float4* __restrict__ pw,
                   float* __restrict__ out) {
  __shared__ u64 red16[16];
  __shared__ int table[TBL];        // 16 KB
  __shared__ int scanb[32];
  __shared__ int mpick[REM];
  __shared__ u64 cand[CCAP];        // 16 KB
  __shared__ int gsorted[REM];
  __shared__ int head_i[16];
  __shared__ int head_bk[16];
  __shared__ int sh[8];             // 0:rhv 1:first_valid 2:has_radius 6:B 7:ok

  const int b = blockIdx.x, t = threadIdx.x;
  const int vmode = flagp[0];
  const float* xyzb = xyz + (size_t)b * NPTS * 3;
  const int* midb = mask_id + (size_t)b * NPTS;
  const float* exb = extra + (size_t)b * NPTS;
  const float* glb = glob + (size_t)b * NPTS;

  if (t < 8) sh[t] = 0;
  if (t == 1) sh[1] = 0x7FFFFFFF;
  if (t < 16) gsorted[t] = -1;      // gripper winners default
  __syncthreads();

  // ---- validity bits (element i = k*1024 + t) ----
  u32 vbits = 0;
#pragma unroll
  for (int k = 0; k < KPER; k++) {
    int i = k * NTHR1 + t;
    if (is_valid_el(validp, vmode, (long long)b * NPTS + i)) vbits |= 1u << k;
  }
  if (vbits) {
    atomicOr(&sh[0], 1);
    atomicMin(&sh[1], (__ffs(vbits) - 1) * NTHR1 + t);
  }

  // ---- gripper distances + packed point array for knn ----
  float gx = state[b * 8 + 0], gy = state[b * 8 + 1], gz = state[b * 8 + 2];
  float gd[KPER];
  u32 inr = 0;
#pragma unroll
  for (int k = 0; k < KPER; k++) {
    int i = k * NTHR1 + t;
    float px = xyzb[3 * i], py = xyzb[3 * i + 1], pz = xyzb[3 * i + 2];
    float dx = px - gx, dy = py - gy, dz = pz - gz;
    float d = sqrtf((dx * dx + dy * dy) + dz * dz);
    gd[k] = d;
    bool vb = (vbits >> k) & 1u;
    if (vb && d <= 0.1f) inr |= 1u << k;
    if (pw) {
      float sb = __fadd_rn(__fadd_rn(__fmul_rn(px, px), __fmul_rn(py, py)), __fmul_rn(pz, pz));
      pw[(size_t)b * NPTS + i] = make_float4(px, py, pz, vb ? sb : INFINITY);
    }
  }
  if (inr) atomicOr(&sh[2], 1);
  __syncthreads();

  const int rhv = sh[0];
  const int first_valid = rhv ? sh[1] : 0;
  const u32 elig = vbits & (sh[2] ? inr : 0xFFFFu);
  u32 sel = 0;

  // ---- gripper: exact ordered top-16 of (gdist asc, idx asc) over eligible ----
  {
    u32 ek[KPER];
#pragma unroll
    for (int k = 0; k < KPER; k++) ek[k] = __float_as_uint(gd[k]);  // gd>=0: bits asc
    topk_select<true, true>(ek, nullptr, elig, 16, table, cand, scanb, sh, gsorted, t);
    if (sh[7]) {
      if (t < 16) {
        int g = gsorted[t];
        head_i[t] = (g >= 0) ? g : first_valid;
        head_bk[t] = (g >= 0) ? 1 : -1;
      }
      __syncthreads();
      for (int j = 0; j < 16; j++) {
        if (head_bk[j] == 1) {
          int ix = head_i[j];
          if ((ix & (NTHR1 - 1)) == t) sel |= 1u << (ix >> 10);
        }
      }
    } else {
      // pathological-ties fallback: iterative extraction
      for (int it = 0; it < 16; ++it) {
        u64 best = ~0ull;
#pragma unroll
        for (int k = 0; k < KPER; k++) {
          if (((elig >> k) & 1u) && !((sel >> k) & 1u)) {
            u64 key = ((u64)__float_as_uint(gd[k]) << 32) | (u32)(k * NTHR1 + t);
            if (key < best) best = key;
          }
        }
        u64 w = block_min_u64(best, red16, t);
        bool keep = (w >> 32) < 0x7F800000ull;
        int idx = (int)(w & 0xFFFFFFFFu);
        if (t == 0) { head_i[it] = keep ? idx : first_valid; head_bk[it] = keep ? 1 : -1; }
        if (keep && (idx & (NTHR1 - 1)) == t) sel |= 1u << (idx >> 10);
      }
      __syncthreads();
    }
  }

  // ---- mask stage: min index per distinct mask_id among candidates ----
  for (int j = t; j < TBL; j += NTHR1) table[j] = 0x7FFFFFFF;
  __syncthreads();
#pragma unroll
  for (int k = 0; k < KPER; k++) {
    if (((vbits >> k) & 1u) && !((sel >> k) & 1u)) {
      int i = k * NTHR1 + t;
      int id = midb[i];
      if ((u32)id < TBL) atomicMin(&table[id], i);
    }
  }
  __syncthreads();
  int cnt = 0;
#pragma unroll
  for (int q = 0; q < 4; q++) cnt += (table[4 * t + q] != 0x7FFFFFFF);
  int mtot;
  int excl = block_excl_scan(cnt, scanb, t, &mtot);
  {
    int pos = excl;
#pragma unroll
    for (int q = 0; q < 4; q++) {
      int v = table[4 * t + q];
      if (v != 0x7FFFFFFF) { if (pos < REM) mpick[pos] = v; pos++; }
    }
  }
  __syncthreads();
  const int nm = min(mtot, REM);
  for (int j = 0; j < nm; j++) {
    int p = mpick[j];
    if ((p & (NTHR1 - 1)) == t) sel |= 1u << (p >> 10);
  }

  // ---- extra stage (only active when < 8 distinct mask ids) ----
  u32 extra_used = 0;
  if (nm < 8 && rhv) {
    u32 extrbits = 0;
    for (int j = 0; j < 8; j++) {
      u64 best = ~0ull;
#pragma unroll
      for (int k = 0; k < KPER; k++) {
        if (((vbits >> k) & 1u) && !((sel >> k) & 1u) && !((extrbits >> k) & 1u)) {
          int i = k * NTHR1 + t;
          u64 key = ((u64)desc_enc(exb[i]) << 32) | (u32)i;
          if (key < best) best = key;
        }
      }
      u64 w = block_min_u64(best, red16, t);
      if (w == ~0ull) break;
      int idx = (int)(w & 0xFFFFFFFFu);
      bool fin = enc_finite((u32)(w >> 32));
      if ((idx & (NTHR1 - 1)) == t) extrbits |= 1u << (idx >> 10);
      if (j >= nm && fin) {
        extra_used |= 1u << j;
        if (t == 0) mpick[j] = idx;
        if ((idx & (NTHR1 - 1)) == t) sel |= 1u << (idx >> 10);
      }
    }
    __syncthreads();
  }

  // ---- global stage: exact ordered top-1008 of (global_score desc, idx asc) ----
  {
    u32 cbits = vbits & ~sel;
    u32 ek[KPER], bk[KPER];
#pragma unroll
    for (int k = 0; k < KPER; k++) {
      if ((cbits >> k) & 1u) {
        float f = glb[k * NTHR1 + t];
        ek[k] = desc_enc(f);
        float g = fminf(fmaxf(f, 0.0f), 0.99999994f);
        bk[k] = 4095u - (u32)(g * 4096.0f);
      } else { ek[k] = 0xFFFFFFFFu; bk[k] = 4095u; }
    }
    for (int j = t; j < REM; j += NTHR1) gsorted[j] = -1;
    topk_select<false, false>(ek, bk, cbits, REM, table, cand, scanb, sh, gsorted, t);
    if (!sh[7]) {
      u32 gext = 0;
      for (int j = 0; j < REM; j++) {
        u64 best = ~0ull;
#pragma unroll
        for (int k = 0; k < KPER; k++) {
          if (((cbits >> k) & 1u) && !((gext >> k) & 1u)) {
            u64 key = ((u64)ek[k] << 32) | (u32)(k * NTHR1 + t);
            if (key < best) best = key;
          }
        }
        u64 w = block_min_u64(best, red16, t);
        if (w == ~0ull) break;
        int idx = (int)(w & 0xFFFFFFFFu);
        if ((idx & (NTHR1 - 1)) == t) gext |= 1u << (idx >> 10);
        if (t == 0) gsorted[j] = enc_finite((u32)(w >> 32)) ? idx : (idx | (int)0x80000000);
      }
      __syncthreads();
    }
  }

  // ---- emit out_idx / out_valid / out_bucket / supernode_xyz ----
  {
    int slot = t;
    int idx, bucket;
    if (slot < 16) {
      idx = head_i[slot];
      bucket = head_bk[slot];
    } else {
      int jj = slot - 16;
      bool mk = (jj < nm) || (jj < 8 && ((extra_used >> jj) & 1u));
      if (mk) { idx = mpick[jj]; bucket = 2; }
      else {
        int g = gsorted[jj];
        if (rhv && g >= 0) { idx = g; bucket = 0; }
        else { idx = first_valid; bucket = -1; }
      }
    }
    bool ov = rhv && is_valid_el(validp, vmode, (long long)b * NPTS + idx);
    int ob = ov ? bucket : -1;
    size_t o = (size_t)b * M_SN + slot;
    out[O3 + o] = (float)idx;
    out[O4 + o] = ov ? 1.0f : 0.0f;
    out[O5 + o] = (float)ob;
    out[O1 + 3 * o + 0] = xyzb[3 * idx + 0];
    out[O1 + 3 * o + 1] = xyzb[3 * idx + 1];
    out[O1 + 3 * o + 2] = xyzb[3 * idx + 2];
  }
}

// ---------------- K2: KNN-16 distance scan (one supernode per WAVE64) ----------------
// R8's structure, widened 32->64 lanes per supernode: 64 points per iteration,
// wave-wide ballot, WAVE-UNIFORM accept drain (removes the dual-group divergence
// that serialized two groups' insert chains per wave). kq refresh deferred to once
// per ballot (kq frozen during drain -> ballot is the exact accept set; removes a
// dependent shuffle per insert). Seed: 21-stage bitonic sort of the first 64 u64
// keys (desc_enc(q)<<32)|idx -- unique keys => exact (q desc, idx asc) order.
#define NTHR2 256
#define CH 1024
#define SNB 4              // supernodes per knn block (4 waves, 1 sn each)
#define SPB 8              // merge kernel's supernodes per block (unchanged)

__global__ __launch_bounds__(256, 8)
void knn_kernel(const float* __restrict__ x, const float* __restrict__ xyz,
                const void* __restrict__ validp, const int* __restrict__ flagp,
                const float4* __restrict__ pw, u64* __restrict__ wnws,
                float* __restrict__ out) {
  __shared__ __align__(16) float4 st[CH];           // 16 KB
  __shared__ u64 wn[SNB * KNN];                     // 512 B (nseg==1 emit path)

  const int b = blockIdx.x >> 8;
  const int grp = blockIdx.x & 255;
  const int half = blockIdx.y;
  const int t = threadIdx.x;
  const int g = t >> 6;              // wave id = supernode within block
  const int lane = t & 63;
  const int m = grp * SNB + g;
  const float* xyzb = xyz + (size_t)b * NPTS * 3;
  const long long gbase = (long long)b * NPTS;

  const int sidx = (int)out[O3 + (size_t)b * M_SN + m];
  float ax, ay, az;
  if (pw) { float4 c = pw[gbase + sidx]; ax = c.x; ay = c.y; az = c.z; }
  else { ax = xyzb[3 * sidx]; ay = xyzb[3 * sidx + 1]; az = xyzb[3 * sidx + 2]; }
  const float a2x = ax + ax, a2y = ay + ay, a2z = az + az;

  float ld = -INFINITY;   // lane = lane-th LARGEST q seen so far (lanes 0-15 = answer)
  int li = 0;
  float kq = -INFINITY;   // wave 16th-largest q (replicated)

  const int vmode = pw ? 0 : flagp[0];
  const int cbeg = wnws ? half * HALFPTS : 0;
  const int cend = wnws ? cbeg + HALFPTS : NPTS;

  for (int c0 = cbeg; c0 < cend; c0 += CH) {
    if (pw) {
      const float4* src = pw + gbase + c0;
#pragma unroll
      for (int qq = 0; qq < CH / NTHR2; qq++) st[t + qq * NTHR2] = src[t + qq * NTHR2];
    } else {
      for (int p = t; p < CH; p += NTHR2) {
        float px = xyzb[3 * (c0 + p)], py = xyzb[3 * (c0 + p) + 1], pz = xyzb[3 * (c0 + p) + 2];
        bool v = is_valid_el(validp, vmode, gbase + c0 + p);
        float sb = __fadd_rn(__fadd_rn(__fmul_rn(px, px), __fmul_rn(py, py)), __fmul_rn(pz, pz));
        st[p] = make_float4(px, py, pz, v ? sb : INFINITY);
      }
    }
    __syncthreads();

    int jstart = 0;
    if (c0 == cbeg) {
      // seed: bitonic sort of first 64 keys ku=(desc_enc(q)<<32)|idx, ascending
      // (unique keys -> exact (q desc, idx asc) order; lane = lane-th best)
      float4 v = st[lane];
      float qv = __builtin_fmaf(a2x, v.x, __builtin_fmaf(a2y, v.y, __builtin_fmaf(a2z, v.z, -v.w)));
      u64 ku = ((u64)desc_enc(qv) << 32) | (u32)(c0 + lane);
#pragma unroll
      for (int kk = 2; kk <= 64; kk <<= 1) {
#pragma unroll
        for (int jj = kk >> 1; jj > 0; jj >>= 1) {
          u32 olo = (u32)__shfl_xor((int)(u32)(ku & 0xFFFFFFFFu), jj, 64);
          u32 ohi = (u32)__shfl_xor((int)(u32)(ku >> 32), jj, 64);
          u64 o = ((u64)ohi << 32) | olo;
          bool keepmin = ((lane & jj) == 0) == ((lane & kk) == 0);
          ku = ((ku < o) == keepmin) ? ku : o;
        }
      }
      ld = desc_dec((u32)(ku >> 32));
      li = (int)(u32)(ku & 0xFFFFFFFFu);
      kq = __shfl(ld, 15, 64);
      jstart = 1;
    }

#pragma unroll 4
    for (int j = jstart; j < CH / 64; j++) {
      float4 v = st[lane + 64 * j];
      float qv = __builtin_fmaf(a2x, v.x, __builtin_fmaf(a2y, v.y, __builtin_fmaf(a2z, v.z, -v.w)));
      u64 bal = __ballot(qv > kq);
      if (bal) {                       // wave-uniform drain, kq frozen (exact set)
        do {
          int bb = __ffsll(bal) - 1;
          bal &= bal - 1;
          float kd = __shfl(qv, bb, 64);
          int ki = c0 + 64 * j + bb;
          bool gt = ld < kd;           // strict -> idx-asc ties (ascending arrival)
          float sd = __shfl_up(ld, 1, 64);
          int si = __shfl_up(li, 1, 64);
          int pg = __shfl_up(gt ? 1 : 0, 1, 64);
          if (lane == 0) pg = 0;
          ld = gt ? (pg ? sd : kd) : ld;
          li = gt ? (pg ? si : ki) : li;
        } while (bal);
        kq = __shfl(ld, 15, 64);       // refresh once per accepted batch
      }
    }
    __syncthreads();
  }

  if (wnws) {
    if (lane < KNN)
      wnws[((size_t)half * BF + b) * M_SN * KNN + (size_t)m * KNN + lane] =
          ((u64)desc_enc(ld) << 32) | (u32)li;
    return;
  }

  // non-split fallback: emit directly
  if (lane < KNN) wn[g * KNN + lane] = ((u64)desc_enc(ld) << 32) | (u32)li;
  __syncthreads();
  for (int r = t; r < SNB * KNN; r += NTHR2) {
    u64 key = wn[r];
    int ni = (int)(key & (u64)(NPTS - 1));
    int mm = grp * SNB + (r >> 4);
    size_t o2 = ((size_t)b * M_SN + mm) * KNN + (r & 15);
    out[O2 + o2] = enc_finite((u32)(key >> 32)) ? 1.0f : 0.0f;
    const float4* src = (const float4*)(x + (gbase + ni) * CCH);
    float4* dst = (float4*)(out + O0 + o2 * CCH);
#pragma unroll
    for (int q = 0; q < 16; q++) dst[q] = src[q];
  }
}

// ---------------- K3: merge the two half-range top-16 lists + emit ----------------
__global__ __launch_bounds__(256)
void knn_merge_kernel(const float* __restrict__ x, const u64* __restrict__ wnws,
                      float* __restrict__ out) {
  __shared__ u64 wn[SPB * KNN];
  const int b = blockIdx.x >> 7;
  const int grp = blockIdx.x & 127;
  const int t = threadIdx.x;
  const int sl = t >> 5;
  const int sub = t & 31;
  const int m = grp * SPB + sl;

  // lanes 0-15: half0 list, lanes 16-31: half1 list (each sorted ascending by key)
  const int h = sub >> 4, k = sub & 15;
  u64 my = wnws[((size_t)h * BF + b) * M_SN * KNN + (size_t)m * KNN + k];
  const int obase = (1 - h) << 4;
  int cnt2 = 0;
#pragma unroll
  for (int j = 0; j < 16; j++) {
    u64 o = shfl64_grp(my, obase + j);
    cnt2 += h ? (o <= my) : (o < my);   // stable merge: half0 wins ties
  }
  int rank = k + cnt2;
  if (rank < KNN) wn[sl * KNN + rank] = my;
  __syncthreads();

  {
    int s2 = t >> 5;
    int k2 = (t >> 1) & 15;
    int hf = t & 1;
    int mm = grp * SPB + s2;
    u64 key = wn[s2 * KNN + k2];
    int ni = (int)(key & (u64)(NPTS - 1));
    size_t o2 = ((size_t)b * M_SN + mm) * KNN + k2;
    if (hf == 0) out[O2 + o2] = enc_finite((u32)(key >> 32)) ? 1.0f : 0.0f;
    const float4* src = (const float4*)(x + ((size_t)b * NPTS + ni) * CCH);
    float4* dst = (float4*)(out + O0 + o2 * CCH);
#pragma unroll
    for (int q = 0; q < 8; q++) dst[hf * 8 + q] = src[hf * 8 + q];
  }
}

extern "C" void kernel_launch(void* const* d_in, const int* in_sizes, int n_in,
                              void* d_out, int out_size, void* d_ws, size_t ws_size,
                              hipStream_t stream) {
  const float* x = (const float*)d_in[0];
  const float* xyz = (const float*)d_in[1];
  const void* valid = d_in[2];
  const float* state = (const float*)d_in[3];
  const int* mask_id = (const int*)d_in[4];
  const float* extra = (const float*)d_in[5];
  const float* glob = (const float*)d_in[6];
  float* out = (float*)d_out;
  int* flag = (int*)d_ws;

  float4* pw = nullptr;
  u64* wnws = nullptr;
  if (ws_size >= PW_OFF + PW_BYTES) pw = (float4*)((char*)d_ws + PW_OFF);
  if (pw && ws_size >= PW_OFF + PW_BYTES + WN_BYTES)
    wnws = (u64*)((char*)d_ws + PW_OFF + PW_BYTES);

  // Runtime storage probe (proven; NEVER infer from in_sizes -- broke out_idx in R2).
  hipMemsetAsync(flag, 0, 4, stream);
  detect_valid<<<64, 1024, 0, stream>>>((const unsigned*)valid, in_sizes[2] / 4, flag);
  sample_kernel<<<BF, NTHR1, 0, stream>>>(xyz, valid, state, mask_id, extra, glob, flag, pw, out);
  dim3 kg(BF * 256, wnws ? 2 : 1);
  knn_kernel<<<kg, NTHR2, 0, stream>>>(x, xyz, valid, flag, pw, wnws, out);
  if (wnws) knn_merge_kernel<<<BF * 128, NTHR2, 0, stream>>>(x, wnws, out);
}

// Round 10
// 253.132 us; speedup vs baseline: 1.4132x; 1.0316x over previous
//
#include <hip/hip_runtime.h>
#include <math.h>

typedef unsigned long long u64;
typedef unsigned int u32;

#define BF 8
#define NPTS 16384
#define HALFPTS 8192
#define M_SN 1024
#define CCH 64
#define KNN 16
#define NTHR1 1024
#define KPER 16            // NPTS / NTHR1
#define TBL 4096
#define CCAP 2048
#define REM 1008           // M - 16 gripper slots

// output layout (flat float32, concatenated in return order)
constexpr size_t O0 = 0;                 // neighbor_feats 8*1024*16*64
constexpr size_t O1 = 8388608;           // supernode_xyz 8*1024*3
constexpr size_t O2 = 8413184;           // neighbor_mask 8*1024*16
constexpr size_t O3 = 8544256;           // out_idx 8*1024
constexpr size_t O4 = 8552448;           // out_valid 8*1024
constexpr size_t O5 = 8560640;           // out_bucket 8*1024

// workspace layout: [0]=flag, PW_OFF: packed float4 points, then split wn lists
#define PW_OFF ((size_t)256)
#define PW_BYTES ((size_t)BF * NPTS * 16)          // 2 MiB
#define WN_BYTES ((size_t)2 * BF * M_SN * KNN * 8) // 2 MiB

__device__ __forceinline__ bool is_valid_el(const void* vp, int mode, long long i) {
  if (mode == 1) return ((const unsigned char*)vp)[i] != 0;
  if (mode == 2) return ((const float*)vp)[i] != 0.0f;
  return ((const int*)vp)[i] != 0;
}

// monotone-decreasing encode: larger float -> smaller u32 (NaN sorts first; -inf last)
__device__ __forceinline__ u32 desc_enc(float f) {
  u32 u = __float_as_uint(f);
  u32 s = (u & 0x80000000u) ? ~u : (u | 0x80000000u);
  return ~s;
}
__device__ __forceinline__ float desc_dec(u32 e) {   // exact inverse of desc_enc
  u32 s = ~e;
  u32 u = (s & 0x80000000u) ? (s & 0x7FFFFFFFu) : ~s;
  return __uint_as_float(u);
}
__device__ __forceinline__ bool enc_finite(u32 d) {
  u32 s = ~d;
  u32 u = (s & 0x80000000u) ? (s & 0x7FFFFFFFu) : ~s;
  return (u & 0x7F800000u) != 0x7F800000u;
}

__device__ __forceinline__ u64 wave_min_u64(u64 v) {
#pragma unroll
  for (int d = 32; d >= 1; d >>= 1) {
    u32 lo = __shfl_xor((u32)(v & 0xFFFFFFFFu), d, 64);
    u32 hi = __shfl_xor((u32)(v >> 32), d, 64);
    u64 o = ((u64)hi << 32) | lo;
    if (o < v) v = o;
  }
  return v;
}

__device__ __forceinline__ u64 block_min_u64(u64 v, u64* red16, int t) {
  v = wave_min_u64(v);
  if ((t & 63) == 0) red16[t >> 6] = v;
  __syncthreads();
  if (t < 64) {
    u64 x = red16[t & 15];
    x = wave_min_u64(x);
    if (t == 0) red16[0] = x;
  }
  __syncthreads();
  u64 r = red16[0];
  __syncthreads();
  return r;
}

__device__ __forceinline__ int block_excl_scan(int val, int* scanb, int t, int* tot) {
  int incl = val;
#pragma unroll
  for (int d = 1; d < 64; d <<= 1) {
    int v = __shfl_up(incl, d, 64);
    if ((t & 63) >= d) incl += v;
  }
  if ((t & 63) == 63) scanb[t >> 6] = incl;
  __syncthreads();
  if (t < 64) {
    int ws = (t < 16) ? scanb[t] : 0;
#pragma unroll
    for (int d = 1; d < 16; d <<= 1) {
      int v = __shfl_up(ws, d, 64);
      if ((t & 63) >= d) ws += v;
    }
    if (t < 16) scanb[16 + t] = ws;
  }
  __syncthreads();
  int wv = t >> 6;
  int base = (wv == 0) ? 0 : scanb[16 + wv - 1];
  *tot = scanb[16 + 15];
  int r = base + incl - val;
  __syncthreads();
  return r;
}

__device__ __forceinline__ u64 shfl64_grp(u64 v, int src) {   // width-32 partitioned
  u32 lo = (u32)__shfl((int)(u32)(v & 0xFFFFFFFFu), src, 32);
  u32 hi = (u32)__shfl((int)(u32)(v >> 32), src, 32);
  return ((u64)hi << 32) | lo;
}

// ---------------------------------------------------------------------------
// topk_select: exact ordered top-T of (ek asc, idx asc) among cmask candidates.
// ---------------------------------------------------------------------------
template<bool ASC, bool SHIFTBIN>
__device__ __forceinline__ void topk_select(const u32* ek, const u32* bk, u32 cmask,
    int Twant, int* table, u64* cand, int* scanb, int* sh, int* outArr, int t) {
  for (int j = t; j < TBL; j += NTHR1) table[j] = 0;
  if (t == 6) sh[6] = 0x7FFFFFFF;
  if (t == 7) sh[7] = 1;
  __syncthreads();
#pragma unroll
  for (int k = 0; k < KPER; k++) {
    if ((cmask >> k) & 1u) {
      int bin = SHIFTBIN ? (int)(ek[k] >> 20) : (int)bk[k];
      atomicAdd(&table[bin], 1);
    }
  }
  __syncthreads();
  int c_[4]; int c4 = 0;
#pragma unroll
  for (int q = 0; q < 4; q++) { c_[q] = table[4 * t + q]; c4 += c_[q]; }
  int htot;
  int cum = block_excl_scan(c4, scanb, t, &htot);
  const int T = min(Twant, htot);
  int e_ = cum;
#pragma unroll
  for (int q = 0; q < 4; q++) {
    int nx = e_ + c_[q];
    if (T > 0 && e_ < T && nx >= T) atomicMin(&sh[6], 4 * t + q);
    table[4 * t + q] = e_;           // overwrite counts with exclusive cums
    e_ = nx;
  }
  __syncthreads();
  if (T <= 0) return;                // uniform; outArr stays -1; sh[7] stays 1
  const int B = sh[6];
#pragma unroll
  for (int k = 0; k < KPER; k++) {
    if ((cmask >> k) & 1u) {
      int bin = SHIFTBIN ? (int)(ek[k] >> 20) : (int)bk[k];
      if (bin <= B) {
        int pos = atomicAdd(&table[bin], 1);   // grouped placement per bin
        if (pos < CCAP)
          cand[pos] = ((u64)ek[k] << 32) | ((u64)(u32)bin << 14) | (u32)(k * NTHR1 + t);
      }
    }
  }
  __syncthreads();
  const int nc = table[B];           // inclusive end of bin B == total collected
  if (nc <= CCAP) {
    for (int c = t; c < nc; c += NTHR1) {
      u64 key = cand[c];
      int bin = (int)((key >> 14) & 0xFFFu);
      int s = bin ? table[bin - 1] : 0;        // segment start (end of bin-1)
      int e2 = table[bin];                     // segment end
      int r = s;
      for (int j = s; j < e2; j++) r += (cand[j] < key);
      if (r < T) {
        u32 enc = (u32)(key >> 32);
        int ix = (int)(key & 0x3FFFu);
        bool fin = ASC ? (enc < 0x7F800000u) : enc_finite(enc);
        outArr[r] = fin ? ix : (ix | (int)0x80000000);
      }
    }
  } else {
    if (t == 0) sh[7] = 0;
  }
  __syncthreads();
}

// ---------------- K0: detect how `valid` (bool) is stored ----------------
// 64-block grid-stride + atomicMax into pre-zeroed flag (memset on host side).
__global__ void detect_valid(const unsigned* __restrict__ w, int nwords, int* __restrict__ flag) {
  int local = 0;
  for (int i = blockIdx.x * blockDim.x + threadIdx.x; i < nwords; i += gridDim.x * blockDim.x) {
    unsigned v = w[i];
    if (v == 0x3F800000u) local = 2;            // float32 storage
    else if (v != 0u && v != 1u) local = max(local, 1); // packed bytes
  }
#pragma unroll
  for (int d = 32; d >= 1; d >>= 1) local = max(local, __shfl_xor(local, d, 64));
  if ((threadIdx.x & 63) == 0 && local) atomicMax(flag, local);
}

// ---------------- K1: supernode sampling (one block per batch row) ----------------
__global__ __launch_bounds__(1024)
void sample_kernel(const float* __restrict__ xyz, const void* __restrict__ validp,
                   const float* __restrict__ state, const int* __restrict__ mask_id,
                   const float* __restrict__ extra, const float* __restrict__ glob,
                   const int* __restrict__ flagp, float4* __restrict__ pw,
                   float* __restrict__ out) {
  __shared__ u64 red16[16];
  __shared__ int table[TBL];        // 16 KB
  __shared__ int scanb[32];
  __shared__ int mpick[REM];
  __shared__ u64 cand[CCAP];        // 16 KB
  __shared__ int gsorted[REM];
  __shared__ int head_i[16];
  __shared__ int head_bk[16];
  __shared__ int sh[8];             // 0:rhv 1:first_valid 2:has_radius 6:B 7:ok

  const int b = blockIdx.x, t = threadIdx.x;
  const int vmode = flagp[0];
  const float* xyzb = xyz + (size_t)b * NPTS * 3;
  const int* midb = mask_id + (size_t)b * NPTS;
  const float* exb = extra + (size_t)b * NPTS;
  const float* glb = glob + (size_t)b * NPTS;

  if (t < 8) sh[t] = 0;
  if (t == 1) sh[1] = 0x7FFFFFFF;
  if (t < 16) gsorted[t] = -1;      // gripper winners default
  __syncthreads();

  // ---- validity bits (element i = k*1024 + t) ----
  u32 vbits = 0;
#pragma unroll
  for (int k = 0; k < KPER; k++) {
    int i = k * NTHR1 + t;
    if (is_valid_el(validp, vmode, (long long)b * NPTS + i)) vbits |= 1u << k;
  }
  if (vbits) {
    atomicOr(&sh[0], 1);
    atomicMin(&sh[1], (__ffs(vbits) - 1) * NTHR1 + t);
  }

  // ---- gripper distances + packed point array for knn ----
  float gx = state[b * 8 + 0], gy = state[b * 8 + 1], gz = state[b * 8 + 2];
  float gd[KPER];
  u32 inr = 0;
#pragma unroll
  for (int k = 0; k < KPER; k++) {
    int i = k * NTHR1 + t;
    float px = xyzb[3 * i], py = xyzb[3 * i + 1], pz = xyzb[3 * i + 2];
    float dx = px - gx, dy = py - gy, dz = pz - gz;
    float d = sqrtf((dx * dx + dy * dy) + dz * dz);
    gd[k] = d;
    bool vb = (vbits >> k) & 1u;
    if (vb && d <= 0.1f) inr |= 1u << k;
    if (pw) {
      float sb = __fadd_rn(__fadd_rn(__fmul_rn(px, px), __fmul_rn(py, py)), __fmul_rn(pz, pz));
      pw[(size_t)b * NPTS + i] = make_float4(px, py, pz, vb ? sb : INFINITY);
    }
  }
  if (inr) atomicOr(&sh[2], 1);
  __syncthreads();

  const int rhv = sh[0];
  const int first_valid = rhv ? sh[1] : 0;
  const u32 elig = vbits & (sh[2] ? inr : 0xFFFFu);
  u32 sel = 0;

  // ---- gripper: exact ordered top-16 of (gdist asc, idx asc) over eligible ----
  {
    u32 ek[KPER];
#pragma unroll
    for (int k = 0; k < KPER; k++) ek[k] = __float_as_uint(gd[k]);  // gd>=0: bits asc
    topk_select<true, true>(ek, nullptr, elig, 16, table, cand, scanb, sh, gsorted, t);
    if (sh[7]) {
      if (t < 16) {
        int g = gsorted[t];
        head_i[t] = (g >= 0) ? g : first_valid;
        head_bk[t] = (g >= 0) ? 1 : -1;
      }
      __syncthreads();
      for (int j = 0; j < 16; j++) {
        if (head_bk[j] == 1) {
          int ix = head_i[j];
          if ((ix & (NTHR1 - 1)) == t) sel |= 1u << (ix >> 10);
        }
      }
    } else {
      // pathological-ties fallback: iterative extraction
      for (int it = 0; it < 16; ++it) {
        u64 best = ~0ull;
#pragma unroll
        for (int k = 0; k < KPER; k++) {
          if (((elig >> k) & 1u) && !((sel >> k) & 1u)) {
            u64 key = ((u64)__float_as_uint(gd[k]) << 32) | (u32)(k * NTHR1 + t);
            if (key < best) best = key;
          }
        }
        u64 w = block_min_u64(best, red16, t);
        bool keep = (w >> 32) < 0x7F800000ull;
        int idx = (int)(w & 0xFFFFFFFFu);
        if (t == 0) { head_i[it] = keep ? idx : first_valid; head_bk[it] = keep ? 1 : -1; }
        if (keep && (idx & (NTHR1 - 1)) == t) sel |= 1u << (idx >> 10);
      }
      __syncthreads();
    }
  }

  // ---- mask stage: min index per distinct mask_id among candidates ----
  for (int j = t; j < TBL; j += NTHR1) table[j] = 0x7FFFFFFF;
  __syncthreads();
#pragma unroll
  for (int k = 0; k < KPER; k++) {
    if (((vbits >> k) & 1u) && !((sel >> k) & 1u)) {
      int i = k * NTHR1 + t;
      int id = midb[i];
      if ((u32)id < TBL) atomicMin(&table[id], i);
    }
  }
  __syncthreads();
  int cnt = 0;
#pragma unroll
  for (int q = 0; q < 4; q++) cnt += (table[4 * t + q] != 0x7FFFFFFF);
  int mtot;
  int excl = block_excl_scan(cnt, scanb, t, &mtot);
  {
    int pos = excl;
#pragma unroll
    for (int q = 0; q < 4; q++) {
      int v = table[4 * t + q];
      if (v != 0x7FFFFFFF) { if (pos < REM) mpick[pos] = v; pos++; }
    }
  }
  __syncthreads();
  const int nm = min(mtot, REM);
  for (int j = 0; j < nm; j++) {
    int p = mpick[j];
    if ((p & (NTHR1 - 1)) == t) sel |= 1u << (p >> 10);
  }

  // ---- extra stage (only active when < 8 distinct mask ids) ----
  u32 extra_used = 0;
  if (nm < 8 && rhv) {
    u32 extrbits = 0;
    for (int j = 0; j < 8; j++) {
      u64 best = ~0ull;
#pragma unroll
      for (int k = 0; k < KPER; k++) {
        if (((vbits >> k) & 1u) && !((sel >> k) & 1u) && !((extrbits >> k) & 1u)) {
          int i = k * NTHR1 + t;
          u64 key = ((u64)desc_enc(exb[i]) << 32) | (u32)i;
          if (key < best) best = key;
        }
      }
      u64 w = block_min_u64(best, red16, t);
      if (w == ~0ull) break;
      int idx = (int)(w & 0xFFFFFFFFu);
      bool fin = enc_finite((u32)(w >> 32));
      if ((idx & (NTHR1 - 1)) == t) extrbits |= 1u << (idx >> 10);
      if (j >= nm && fin) {
        extra_used |= 1u << j;
        if (t == 0) mpick[j] = idx;
        if ((idx & (NTHR1 - 1)) == t) sel |= 1u << (idx >> 10);
      }
    }
    __syncthreads();
  }

  // ---- global stage: exact ordered top-1008 of (global_score desc, idx asc) ----
  {
    u32 cbits = vbits & ~sel;
    u32 ek[KPER], bk[KPER];
#pragma unroll
    for (int k = 0; k < KPER; k++) {
      if ((cbits >> k) & 1u) {
        float f = glb[k * NTHR1 + t];
        ek[k] = desc_enc(f);
        float g = fminf(fmaxf(f, 0.0f), 0.99999994f);
        bk[k] = 4095u - (u32)(g * 4096.0f);
      } else { ek[k] = 0xFFFFFFFFu; bk[k] = 4095u; }
    }
    for (int j = t; j < REM; j += NTHR1) gsorted[j] = -1;
    topk_select<false, false>(ek, bk, cbits, REM, table, cand, scanb, sh, gsorted, t);
    if (!sh[7]) {
      u32 gext = 0;
      for (int j = 0; j < REM; j++) {
        u64 best = ~0ull;
#pragma unroll
        for (int k = 0; k < KPER; k++) {
          if (((cbits >> k) & 1u) && !((gext >> k) & 1u)) {
            u64 key = ((u64)ek[k] << 32) | (u32)(k * NTHR1 + t);
            if (key < best) best = key;
          }
        }
        u64 w = block_min_u64(best, red16, t);
        if (w == ~0ull) break;
        int idx = (int)(w & 0xFFFFFFFFu);
        if ((idx & (NTHR1 - 1)) == t) gext |= 1u << (idx >> 10);
        if (t == 0) gsorted[j] = enc_finite((u32)(w >> 32)) ? idx : (idx | (int)0x80000000);
      }
      __syncthreads();
    }
  }

  // ---- emit out_idx / out_valid / out_bucket / supernode_xyz ----
  {
    int slot = t;
    int idx, bucket;
    if (slot < 16) {
      idx = head_i[slot];
      bucket = head_bk[slot];
    } else {
      int jj = slot - 16;
      bool mk = (jj < nm) || (jj < 8 && ((extra_used >> jj) & 1u));
      if (mk) { idx = mpick[jj]; bucket = 2; }
      else {
        int g = gsorted[jj];
        if (rhv && g >= 0) { idx = g; bucket = 0; }
        else { idx = first_valid; bucket = -1; }
      }
    }
    bool ov = rhv && is_valid_el(validp, vmode, (long long)b * NPTS + idx);
    int ob = ov ? bucket : -1;
    size_t o = (size_t)b * M_SN + slot;
    out[O3 + o] = (float)idx;
    out[O4 + o] = ov ? 1.0f : 0.0f;
    out[O5 + o] = (float)ob;
    out[O1 + 3 * o + 0] = xyzb[3 * idx + 0];
    out[O1 + 3 * o + 1] = xyzb[3 * idx + 1];
    out[O1 + 3 * o + 2] = xyzb[3 * idx + 2];
  }
}

// ---------------- K2: KNN-16 distance scan (2 supernodes per WAVE64) ----------------
// One shared ds_read_b128 per point feeds TWO q-evaluations; each sn's ballot +
// drain is wave-uniform and runs sequentially (no intra-wave divergence -- this
// is NOT R5's 32-lane dual-group failure mode). Halves LDS-read instructions and
// total waves; grid = 2048 blocks = 8 blocks/CU x 4 waves = full residency in one
// round. Selection logic per sn is bit-identical to R9's proven wave64 algorithm.
#define NTHR2 256
#define CH 1024
#define SPW 2              // supernodes per wave
#define SNB 8              // supernodes per knn block (4 waves * SPW)
#define SPB 8              // merge kernel's supernodes per block (unchanged)

__global__ __launch_bounds__(256, 8)
void knn_kernel(const float* __restrict__ x, const float* __restrict__ xyz,
                const void* __restrict__ validp, const int* __restrict__ flagp,
                const float4* __restrict__ pw, u64* __restrict__ wnws,
                float* __restrict__ out) {
  __shared__ __align__(16) float4 st[CH];           // 16 KB
  __shared__ u64 wn[SNB * KNN];                     // 1 KB (nseg==1 emit path)

  const int b = blockIdx.x >> 7;
  const int grp = blockIdx.x & 127;
  const int half = blockIdx.y;
  const int t = threadIdx.x;
  const int g = t >> 6;              // wave id
  const int lane = t & 63;
  const int m0 = grp * SNB + g * SPW;
  const float* xyzb = xyz + (size_t)b * NPTS * 3;
  const long long gbase = (long long)b * NPTS;

  float a2x[SPW], a2y[SPW], a2z[SPW];
#pragma unroll
  for (int s = 0; s < SPW; s++) {
    int sidx = (int)out[O3 + (size_t)b * M_SN + m0 + s];
    float ax, ay, az;
    if (pw) { float4 c = pw[gbase + sidx]; ax = c.x; ay = c.y; az = c.z; }
    else { ax = xyzb[3 * sidx]; ay = xyzb[3 * sidx + 1]; az = xyzb[3 * sidx + 2]; }
    a2x[s] = ax + ax; a2y[s] = ay + ay; a2z[s] = az + az;
  }

  float ld[SPW]; int li[SPW]; float kq[SPW];
#pragma unroll
  for (int s = 0; s < SPW; s++) { ld[s] = -INFINITY; li[s] = 0; kq[s] = -INFINITY; }

  const int vmode = pw ? 0 : flagp[0];
  const int cbeg = wnws ? half * HALFPTS : 0;
  const int cend = wnws ? cbeg + HALFPTS : NPTS;

  for (int c0 = cbeg; c0 < cend; c0 += CH) {
    if (pw) {
      const float4* src = pw + gbase + c0;
#pragma unroll
      for (int qq = 0; qq < CH / NTHR2; qq++) st[t + qq * NTHR2] = src[t + qq * NTHR2];
    } else {
      for (int p = t; p < CH; p += NTHR2) {
        float px = xyzb[3 * (c0 + p)], py = xyzb[3 * (c0 + p) + 1], pz = xyzb[3 * (c0 + p) + 2];
        bool v = is_valid_el(validp, vmode, gbase + c0 + p);
        float sb = __fadd_rn(__fadd_rn(__fmul_rn(px, px), __fmul_rn(py, py)), __fmul_rn(pz, pz));
        st[p] = make_float4(px, py, pz, v ? sb : INFINITY);
      }
    }
    __syncthreads();

    int jstart = 0;
    if (c0 == cbeg) {
      // seed both lists: bitonic sort of first 64 keys (desc_enc(q)<<32)|idx,
      // ascending (unique keys -> exact (q desc, idx asc); lane = lane-th best)
      float4 v = st[lane];
#pragma unroll
      for (int s = 0; s < SPW; s++) {
        float qv = __builtin_fmaf(a2x[s], v.x, __builtin_fmaf(a2y[s], v.y, __builtin_fmaf(a2z[s], v.z, -v.w)));
        u64 ku = ((u64)desc_enc(qv) << 32) | (u32)(c0 + lane);
#pragma unroll
        for (int kk = 2; kk <= 64; kk <<= 1) {
#pragma unroll
          for (int jj = kk >> 1; jj > 0; jj >>= 1) {
            u32 olo = (u32)__shfl_xor((int)(u32)(ku & 0xFFFFFFFFu), jj, 64);
            u32 ohi = (u32)__shfl_xor((int)(u32)(ku >> 32), jj, 64);
            u64 o = ((u64)ohi << 32) | olo;
            bool keepmin = ((lane & jj) == 0) == ((lane & kk) == 0);
            ku = ((ku < o) == keepmin) ? ku : o;
          }
        }
        ld[s] = desc_dec((u32)(ku >> 32));
        li[s] = (int)(u32)(ku & 0xFFFFFFFFu);
        kq[s] = __shfl(ld[s], 15, 64);
      }
      jstart = 1;
    }

#pragma unroll 2
    for (int j = jstart; j < CH / 64; j++) {
      float4 v = st[lane + 64 * j];
#pragma unroll
      for (int s = 0; s < SPW; s++) {
        float qv = __builtin_fmaf(a2x[s], v.x, __builtin_fmaf(a2y[s], v.y, __builtin_fmaf(a2z[s], v.z, -v.w)));
        u64 bal = __ballot(qv > kq[s]);
        if (bal) {                     // wave-uniform drain, kq frozen (exact set)
          do {
            int bb = __ffsll(bal) - 1;
            bal &= bal - 1;
            float kd = __shfl(qv, bb, 64);
            int ki = c0 + 64 * j + bb;
            bool gt = ld[s] < kd;      // strict -> idx-asc ties (ascending arrival)
            float sd = __shfl_up(ld[s], 1, 64);
            int si = __shfl_up(li[s], 1, 64);
            int pg = __shfl_up(gt ? 1 : 0, 1, 64);
            if (lane == 0) pg = 0;
            ld[s] = gt ? (pg ? sd : kd) : ld[s];
            li[s] = gt ? (pg ? si : ki) : li[s];
          } while (bal);
          kq[s] = __shfl(ld[s], 15, 64);   // refresh once per accepted batch
        }
      }
    }
    __syncthreads();
  }

  if (wnws) {
#pragma unroll
    for (int s = 0; s < SPW; s++)
      if (lane < KNN)
        wnws[((size_t)half * BF + b) * M_SN * KNN + (size_t)(m0 + s) * KNN + lane] =
            ((u64)desc_enc(ld[s]) << 32) | (u32)li[s];
    return;
  }

  // non-split fallback: emit directly
#pragma unroll
  for (int s = 0; s < SPW; s++)
    if (lane < KNN) wn[(g * SPW + s) * KNN + lane] = ((u64)desc_enc(ld[s]) << 32) | (u32)li[s];
  __syncthreads();
  for (int r = t; r < SNB * KNN; r += NTHR2) {
    u64 key = wn[r];
    int ni = (int)(key & (u64)(NPTS - 1));
    int mm = grp * SNB + (r >> 4);
    size_t o2 = ((size_t)b * M_SN + mm) * KNN + (r & 15);
    out[O2 + o2] = enc_finite((u32)(key >> 32)) ? 1.0f : 0.0f;
    const float4* src = (const float4*)(x + (gbase + ni) * CCH);
    float4* dst = (float4*)(out + O0 + o2 * CCH);
#pragma unroll
    for (int q = 0; q < 16; q++) dst[q] = src[q];
  }
}

// ---------------- K3: merge the two half-range top-16 lists + emit ----------------
__global__ __launch_bounds__(256)
void knn_merge_kernel(const float* __restrict__ x, const u64* __restrict__ wnws,
                      float* __restrict__ out) {
  __shared__ u64 wn[SPB * KNN];
  const int b = blockIdx.x >> 7;
  const int grp = blockIdx.x & 127;
  const int t = threadIdx.x;
  const int sl = t >> 5;
  const int sub = t & 31;
  const int m = grp * SPB + sl;

  // lanes 0-15: half0 list, lanes 16-31: half1 list (each sorted ascending by key)
  const int h = sub >> 4, k = sub & 15;
  u64 my = wnws[((size_t)h * BF + b) * M_SN * KNN + (size_t)m * KNN + k];
  const int obase = (1 - h) << 4;
  int cnt2 = 0;
#pragma unroll
  for (int j = 0; j < 16; j++) {
    u64 o = shfl64_grp(my, obase + j);
    cnt2 += h ? (o <= my) : (o < my);   // stable merge: half0 wins ties
  }
  int rank = k + cnt2;
  if (rank < KNN) wn[sl * KNN + rank] = my;
  __syncthreads();

  {
    int s2 = t >> 5;
    int k2 = (t >> 1) & 15;
    int hf = t & 1;
    int mm = grp * SPB + s2;
    u64 key = wn[s2 * KNN + k2];
    int ni = (int)(key & (u64)(NPTS - 1));
    size_t o2 = ((size_t)b * M_SN + mm) * KNN + k2;
    if (hf == 0) out[O2 + o2] = enc_finite((u32)(key >> 32)) ? 1.0f : 0.0f;
    const float4* src = (const float4*)(x + ((size_t)b * NPTS + ni) * CCH);
    float4* dst = (float4*)(out + O0 + o2 * CCH);
#pragma unroll
    for (int q = 0; q < 8; q++) dst[hf * 8 + q] = src[hf * 8 + q];
  }
}

extern "C" void kernel_launch(void* const* d_in, const int* in_sizes, int n_in,
                              void* d_out, int out_size, void* d_ws, size_t ws_size,
                              hipStream_t stream) {
  const float* x = (const float*)d_in[0];
  const float* xyz = (const float*)d_in[1];
  const void* valid = d_in[2];
  const float* state = (const float*)d_in[3];
  const int* mask_id = (const int*)d_in[4];
  const float* extra = (const float*)d_in[5];
  const float* glob = (const float*)d_in[6];
  float* out = (float*)d_out;
  int* flag = (int*)d_ws;

  float4* pw = nullptr;
  u64* wnws = nullptr;
  if (ws_size >= PW_OFF + PW_BYTES) pw = (float4*)((char*)d_ws + PW_OFF);
  if (pw && ws_size >= PW_OFF + PW_BYTES + WN_BYTES)
    wnws = (u64*)((char*)d_ws + PW_OFF + PW_BYTES);

  // Runtime storage probe (proven; NEVER infer from in_sizes -- broke out_idx in R2).
  hipMemsetAsync(flag, 0, 4, stream);
  detect_valid<<<64, 1024, 0, stream>>>((const unsigned*)valid, in_sizes[2] / 4, flag);
  sample_kernel<<<BF, NTHR1, 0, stream>>>(xyz, valid, state, mask_id, extra, glob, flag, pw, out);
  dim3 kg(BF * 128, wnws ? 2 : 1);
  knn_kernel<<<kg, NTHR2, 0, stream>>>(x, xyz, valid, flag, pw, wnws, out);
  if (wnws) knn_merge_kernel<<<BF * 128, NTHR2, 0, stream>>>(x, wnws, out);
}